// Round 22
// baseline (181.393 us; speedup 1.0000x reference)
//
#include <hip/hip_runtime.h>
#include <math.h>

#define N_NODES 100000
#define N_EDGES 1600000
#define IN_F 64
#define OUT_F 64

// KAN GEMM K layout: k = (path*64 + i)*10 + c; c=0..7 spline bases, c=8 silu,
// c=9 zero pad. K'=1280. Chunk = 16 in-feats = 160 k = 5 MFMA K-steps of 32.
#define K_SLOT 10
#define CH_IF 16
#define AST 172            // A_lds row stride in bf16; bank period 16
#define AGH 33             // agg_lds row stride in u32 (bf16x2); 33%32==1
#define NB 64              // nodes per block (kan)
#define NTHR 256

// bucketed CSR build (fixed capacity)
#define NBUCK 256
#define NBUCK_USED 196
#define BSH 9
#define BCAP 9728          // mean 8192 + 17 sigma
#define BUCK_N 512
#define EPT 8
#define EPB 2048

// ws layout (f32 slots)
#define NODES_PAD 100352
#define WF_U16 (8 * 20 * 512)
#define WG_SLOTS (WF_U16 / 2)
#define CSR_CAP (NBUCK_USED * BCAP)
#define OFF_DINV 0
#define OFF_ROWPTR (OFF_DINV + NODES_PAD)
#define OFF_ROWEND (OFF_ROWPTR + NODES_PAD)
#define OFF_WT (OFF_ROWEND + NODES_PAD)
#define OFF_BF (OFF_WT + WG_SLOTS)
#define OFF_CSR (OFF_BF + 256)
#define FIXED_SLOTS (OFF_CSR + CSR_CAP)
#define XH_SLOTS (N_NODES * IN_F / 2)
#define OFF_XH FIXED_SLOTS
#define FIXED2 (FIXED_SLOTS + XH_SLOTS)
#define AGG_ELEMS (N_NODES * IN_F)

typedef __attribute__((ext_vector_type(8))) short bf16x8;
typedef __attribute__((ext_vector_type(4))) short bf16x4;
typedef __attribute__((ext_vector_type(4))) float f32x4;

__device__ __forceinline__ unsigned int bf16_rne(float v) {
    unsigned int u = __float_as_uint(v);
    u += 0x7FFFu + ((u >> 16) & 1u);
    return u >> 16;
}

// ---- bin edges: LDS counting-sort by bucket -> coalesced pairs write-out ----
// (replaces scattered 8B writes across 196 regions, which caused partial-line
//  write amplification + fetch-on-write in L2)
__global__ __launch_bounds__(256)
void bucket_bin_kernel(const int* __restrict__ ei, int* __restrict__ bf,
                       int2* __restrict__ pairs,
                       const float* __restrict__ x, unsigned short* __restrict__ xh) {
    __shared__ int lh[NBUCK];      // per-bucket count
    __shared__ int lbs[NBUCK];     // scan -> local exclusive base
    __shared__ int lgb[NBUCK];     // global base per bucket
    __shared__ int2 spair[EPB];    // 16384 B staged pairs (sorted by bucket)
    __shared__ int  sdst[EPB];     // 8192 B global dest per staged slot
    int t = threadIdx.x;
    lh[t] = 0;
    __syncthreads();
    int e0 = blockIdx.x * EPB;
    int nE = N_EDGES - e0; if (nE > EPB) nE = EPB; if (nE < 0) nE = 0;
    int d[EPT], s[EPT], lp[EPT];
#pragma unroll
    for (int k = 0; k < EPT; ++k) {
        int idx = k * 256 + t;
        bool ok = idx < nE;
        int e = e0 + idx;
        d[k] = ok ? ei[N_EDGES + e] : -1;
        s[k] = ok ? ei[e] : 0;
        lp[k] = ok ? atomicAdd(&lh[d[k] >> BSH], 1) : 0;
    }
    __syncthreads();
    int v = lh[t];
    lbs[t] = v;
    __syncthreads();
    for (int off = 1; off < NBUCK; off <<= 1) {
        int add = (t >= off) ? lbs[t - off] : 0;
        __syncthreads();
        lbs[t] += add;
        __syncthreads();
    }
    int excl = lbs[t] - v;
    if (v) {
        int r = atomicAdd(&bf[t], v);
        int cap = (t + 1) * BCAP - v;
        lgb[t] = r > cap ? cap : r;   // defensive clamp (never triggers at 17 sigma)
    }
    __syncthreads();
    lbs[t] = excl;
    __syncthreads();
#pragma unroll
    for (int k = 0; k < EPT; ++k) {
        if (d[k] >= 0) {
            int b = d[k] >> BSH;
            int sp = lbs[b] + lp[k];
            spair[sp] = make_int2(d[k], s[k]);
            sdst[sp] = lgb[b] + lp[k];
        }
    }
    __syncthreads();
    // coalesced write-out: consecutive p within a bucket run -> consecutive dest
    for (int p = t; p < nE; p += 256) pairs[sdst[p]] = spair[p];

    // merged xprep: x -> bf16 copy (grid-stride)
    int total = gridDim.x * 256;
    for (int i = blockIdx.x * 256 + t; i * 4 < N_NODES * IN_F; i += total) {
        float4 vv = *(const float4*)&x[i * 4];
        uint2 u;
        u.x = bf16_rne(vv.x) | (bf16_rne(vv.y) << 16);
        u.y = bf16_rne(vv.z) | (bf16_rne(vv.w) << 16);
        *(uint2*)&xh[i * 4] = u;
    }
}

// one block per bucket: local deg hist, scan -> rowptr/rowend/dinv, csr fill
__global__ __launch_bounds__(BUCK_N)
void bucket_build_kernel(const int2* __restrict__ pairs, const int* __restrict__ bf,
                         int* __restrict__ rowptr, int* __restrict__ rowend,
                         float* __restrict__ dinv, int* __restrict__ csr) {
    __shared__ int ldeg[BUCK_N];
    __shared__ int sb[BUCK_N];
    __shared__ int lpos[BUCK_N];
    int t = threadIdx.x;
    int b = blockIdx.x;
    int base = b * BCAP;
    int cnt = bf[b] - base;
    if (cnt > BCAP) cnt = BCAP;
    ldeg[t] = 0;
    __syncthreads();
    for (int j = t; j < cnt; j += BUCK_N) atomicAdd(&ldeg[pairs[base + j].x & (BUCK_N - 1)], 1);
    __syncthreads();
    int v = ldeg[t];
    sb[t] = v;
    __syncthreads();
    for (int off = 1; off < BUCK_N; off <<= 1) {
        int add = (t >= off) ? sb[t - off] : 0;
        __syncthreads();
        sb[t] += add;
        __syncthreads();
    }
    int excl = sb[t] - v;
    int node = (b << BSH) + t;
    if (node < N_NODES) {
        rowptr[node] = base + excl;
        rowend[node] = base + excl + v;
        dinv[node] = (v > 0) ? rsqrtf((float)v) : 0.0f;
    }
    lpos[t] = base + excl;
    __syncthreads();
    for (int j = t; j < cnt; j += BUCK_N) {
        int2 p = pairs[base + j];
        int pos = atomicAdd(&lpos[p.x & (BUCK_N - 1)], 1);
        csr[pos] = p.y;
    }
}

// gather (f32 x): fallback when ws can't hold xh
__global__ __launch_bounds__(256)
void gather_kernel(const float* __restrict__ x, const int* __restrict__ csr,
                   const int* __restrict__ rowptr, const int* __restrict__ rowend,
                   const float* __restrict__ dinv, float* __restrict__ agg) {
    int wid = (int)((blockIdx.x * 256 + threadIdx.x) >> 6);
    int lane = threadIdx.x & 63;
    if (wid >= N_NODES) return;
    int start = rowptr[wid];
    int end = rowend[wid];
    float acc = 0.0f;
    int j = start;
    for (; j + 3 < end; j += 4) {
        int s0 = csr[j], s1 = csr[j + 1], s2 = csr[j + 2], s3 = csr[j + 3];
        float a0 = x[s0 * 64 + lane] * dinv[s0];
        float a1 = x[s1 * 64 + lane] * dinv[s1];
        float a2 = x[s2 * 64 + lane] * dinv[s2];
        float a3 = x[s3 * 64 + lane] * dinv[s3];
        acc += a0 + a1 + a2 + a3;
    }
    for (; j < end; ++j) {
        int s = csr[j];
        acc += x[s * 64 + lane] * dinv[s];
    }
    agg[wid * 64 + lane] = acc * dinv[wid];
}

// ---- fallback (ws too small): f32 atomic scatter ----
__global__ void deg_kernel(const int* __restrict__ ei, float* __restrict__ deg) {
    int e = blockIdx.x * blockDim.x + threadIdx.x;
    if (e < N_EDGES) atomicAdd(&deg[ei[N_EDGES + e]], 1.0f);
}
__global__ void dinv_kernel(float* __restrict__ deg) {
    int n = blockIdx.x * blockDim.x + threadIdx.x;
    if (n < N_NODES) {
        float d = deg[n];
        deg[n] = (d > 0.0f) ? rsqrtf(d) : 0.0f;
    }
}
__global__ void scatter_kernel(const float* __restrict__ x, const int* __restrict__ ei,
                               const float* __restrict__ dinv, float* __restrict__ agg) {
    long long gtid = (long long)blockIdx.x * blockDim.x + threadIdx.x;
    int wid = (int)(gtid >> 6);
    int lane = threadIdx.x & 63;
    if (wid >= N_EDGES) return;
    int s = ei[wid];
    int d = ei[N_EDGES + wid];
    float c = dinv[s] * dinv[d];
    atomicAdd(&agg[d * 64 + lane], x[s * 64 + lane] * c);
}

// Wf in MFMA fragment order + bf cursor init (bf may be null in fallback path)
__global__ void wprep_kernel(const float* __restrict__ bwl, const float* __restrict__ swl,
                             const float* __restrict__ bwc, const float* __restrict__ swc,
                             unsigned short* __restrict__ Wf, int* __restrict__ bf) {
    int gid = blockIdx.x * blockDim.x + threadIdx.x;
    if (bf && gid < NBUCK) bf[gid] = gid * BCAP;
    if (gid >= WF_U16) return;
    int fr = gid >> 9;
    int lj = gid & 511;
    int lane = lj >> 3, j = lj & 7;
    int ch = fr / 20, r2 = fr - ch * 20;
    int s = r2 >> 2, t = r2 & 3;
    int o = t * 16 + (lane & 15);
    int kk = ((lane >> 4) << 3) + s * 32 + j;
    int iL = kk / K_SLOT, c = kk - iL * K_SLOT;
    int i = (ch & 3) * CH_IF + iL;
    int path = ch >> 2;
    const float* bw = path ? bwc : bwl;
    const float* sw = path ? swc : swl;
    float v = 0.0f;
    if (c == 8) v = bw[o * IN_F + i];
    else if (c < 8) v = sw[o * 512 + i * 8 + c];
    Wf[gid] = (unsigned short)bf16_rne(v);
}

// shared feature-write helper
__device__ __forceinline__ void write_feat(unsigned short* Arow, int iL, float v) {
    unsigned int* Au = (unsigned int*)(Arow + iL * K_SLOT);
    float sig = __builtin_amdgcn_rcpf(1.0f + __expf(-v));
    Au[0] = 0u; Au[1] = 0u; Au[2] = 0u; Au[3] = 0u;
    Au[4] = bf16_rne(v * sig);
    float s5 = (v + 2.2f) * 2.5f;
    float fm = floorf(s5);
    int m = (int)fm;
    if (m >= 0 && m <= 10) {
        float t = s5 - fm;
        float omt = 1.0f - t;
        float t2 = t * t, t3 = t2 * t;
        float n0 = omt * omt * omt * (1.0f / 6.0f);
        float n3 = t3 * (1.0f / 6.0f);
        float n1 = 0.66666666f - t2 + 0.5f * t3;
        float n2 = 1.0f - n0 - n1 - n3;
        unsigned short* As = Arow + iL * K_SLOT;
        if (m >= 3)           As[m - 3] = (unsigned short)bf16_rne(n0);
        if (m >= 2 && m <= 9) As[m - 2] = (unsigned short)bf16_rne(n1);
        if (m >= 1 && m <= 8) As[m - 1] = (unsigned short)bf16_rne(n2);
        if (m <= 7)           As[m]     = (unsigned short)bf16_rne(n3);
    }
}

// FUSED gather + MFMA KAN v5 — barrier-free, wave-self-contained, parity-staggered.
// csr read directly from global (broadcast across the 32-lane half -> L1-friendly);
// LDS trimmed to 30.5 KB -> 5 blocks/CU for latency hiding.
__global__ __launch_bounds__(NTHR, 5)
void kan_fused_kernel(const float* __restrict__ x, const unsigned short* __restrict__ xh,
                      const int* __restrict__ csr, const int* __restrict__ rowptr,
                      const int* __restrict__ rowend, const float* __restrict__ dinv,
                      const unsigned short* __restrict__ Wf, float* __restrict__ out) {
    __shared__ __align__(16) unsigned short A_lds[NB * AST];   // 22016 B
    __shared__ unsigned int agg_lds[NB * AGH];                 // 8448 B

    int tid = threadIdx.x;
    int nbase = blockIdx.x * NB;
    int wid = tid >> 6;
    int lane = tid & 63;
    int nloc0 = (wid << 4) + (lane & 15);
    int q = lane >> 4;
    int node0 = nbase + nloc0;
    bool ok0 = node0 < N_NODES;

    const float4 z4 = make_float4(0.f, 0.f, 0.f, 0.f);
    float4 vx[4];
#pragma unroll
    for (int c = 0; c < 4; ++c)
        vx[c] = ok0 ? *(const float4*)&x[node0 * 64 + c * CH_IF + q * 4] : z4;

    f32x4 acc[4];
#pragma unroll
    for (int t = 0; t < 4; ++t) acc[t] = (f32x4){0.f, 0.f, 0.f, 0.f};

    int kfrag = (lane >> 4) * 8;
    const unsigned short* Abase = &A_lds[nloc0 * AST + kfrag];
    unsigned short* Arow = &A_lds[nloc0 * AST];
    const bf16x8* Bbase = (const bf16x8*)Wf + lane;

    auto do_chunk = [&](int chunk) {
        float vv[4];
        if (chunk < 4) {
            vv[0] = vx[chunk].x; vv[1] = vx[chunk].y; vv[2] = vx[chunk].z; vv[3] = vx[chunk].w;
        } else {
            int b2 = (chunk - 4) * 8 + q * 2;
            unsigned u0 = agg_lds[nloc0 * AGH + b2];
            unsigned u1 = agg_lds[nloc0 * AGH + b2 + 1];
            vv[0] = __uint_as_float(u0 << 16);
            vv[1] = __uint_as_float(u0 & 0xFFFF0000u);
            vv[2] = __uint_as_float(u1 << 16);
            vv[3] = __uint_as_float(u1 & 0xFFFF0000u);
        }
#pragma unroll
        for (int jj = 0; jj < 4; ++jj) write_feat(Arow, q * 4 + jj, vv[jj]);
#pragma unroll
        for (int s = 0; s < 5; ++s) {
            bf16x4 alo = *(const bf16x4*)(Abase + s * 32);
            bf16x4 ahi = *(const bf16x4*)(Abase + s * 32 + 4);
            bf16x8 a = __builtin_shufflevector(alo, ahi, 0, 1, 2, 3, 4, 5, 6, 7);
#pragma unroll
            for (int t = 0; t < 4; ++t) {
                bf16x8 b = Bbase[((chunk * 5 + s) * 4 + t) * 64];
                acc[t] = __builtin_amdgcn_mfma_f32_16x16x32_bf16(a, b, acc[t], 0, 0, 0);
            }
        }
    };

    auto do_gather = [&]() {
        int half = lane >> 5;
        int l = lane & 31;
        const unsigned int* xh32 = (const unsigned int*)xh;
        for (int p = 0; p < 8; ++p) {
            int nloc = (wid << 4) + (p << 1) + half;
            int nd = nbase + nloc;
            float ax = 0.f, ay = 0.f, dn = 0.f;
            if (nd < N_NODES) {
                dn = dinv[nd];
                int j = rowptr[nd];
                int end = rowend[nd];
                for (; j + 15 < end; j += 16) {
                    int sa[16]; unsigned ua[16]; float da[16];
#pragma unroll
                    for (int k = 0; k < 16; ++k) sa[k] = csr[j + k];
#pragma unroll
                    for (int k = 0; k < 16; ++k) ua[k] = xh32[sa[k] * 32 + l];
#pragma unroll
                    for (int k = 0; k < 16; ++k) da[k] = dinv[sa[k]];
#pragma unroll
                    for (int k = 0; k < 16; ++k) {
                        ax += __uint_as_float(ua[k] << 16) * da[k];
                        ay += __uint_as_float(ua[k] & 0xFFFF0000u) * da[k];
                    }
                }
                for (; j + 3 < end; j += 4) {
                    int s0 = csr[j], s1 = csr[j + 1], s2 = csr[j + 2], s3 = csr[j + 3];
                    unsigned u0 = xh32[s0 * 32 + l], u1 = xh32[s1 * 32 + l];
                    unsigned u2 = xh32[s2 * 32 + l], u3 = xh32[s3 * 32 + l];
                    float d0 = dinv[s0], d1 = dinv[s1], d2 = dinv[s2], d3 = dinv[s3];
                    ax += __uint_as_float(u0 << 16) * d0 + __uint_as_float(u1 << 16) * d1
                        + __uint_as_float(u2 << 16) * d2 + __uint_as_float(u3 << 16) * d3;
                    ay += __uint_as_float(u0 & 0xFFFF0000u) * d0 + __uint_as_float(u1 & 0xFFFF0000u) * d1
                        + __uint_as_float(u2 & 0xFFFF0000u) * d2 + __uint_as_float(u3 & 0xFFFF0000u) * d3;
                }
                for (; j < end; ++j) {
                    int s = csr[j];
                    unsigned u = xh32[s * 32 + l];
                    float d = dinv[s];
                    ax += __uint_as_float(u << 16) * d;
                    ay += __uint_as_float(u & 0xFFFF0000u) * d;
                }
            }
            agg_lds[nloc * AGH + l] = bf16_rne(ax * dn) | (bf16_rne(ay * dn) << 16);
        }
    };

    if ((blockIdx.x & 1) == 0) {
#pragma unroll
        for (int c = 0; c < 4; ++c) do_chunk(c);
        do_gather();
#pragma unroll
        for (int c = 4; c < 8; ++c) do_chunk(c);
    } else {
        do_gather();
#pragma unroll
        for (int c = 0; c < 8; ++c) do_chunk(c);
    }

#pragma unroll
    for (int t = 0; t < 4; ++t) {
#pragma unroll
        for (int r = 0; r < 4; ++r) {
            int nd = nbase + (wid << 4) + (lane >> 4) * 4 + r;
            if (nd < N_NODES) out[nd * 64 + t * 16 + (lane & 15)] = acc[t][r];
        }
    }
}

// unfused MFMA KAN (fallback when no xh): reads agg from global; keeps barriers
__global__ __launch_bounds__(NTHR, 8)
void kan_mfma_kernel(const float* __restrict__ x, const float* __restrict__ agg,
                     const unsigned short* __restrict__ Wf, float* __restrict__ out) {
    __shared__ __align__(16) unsigned short A_lds[NB * AST];

    int tid = threadIdx.x;
    int nbase = blockIdx.x * NB;
    int wid = tid >> 6;
    int lane = tid & 63;
    int n = tid & (NB - 1);
    int grp = wid;
    int node = nbase + n;
    bool ok = node < N_NODES;
    const float4 z4 = make_float4(0.f, 0.f, 0.f, 0.f);
    float4 vx[4], va[4];
#pragma unroll
    for (int qq = 0; qq < 4; ++qq)
        vx[qq] = ok ? *(const float4*)&x[node * 64 + qq * CH_IF + grp * 4] : z4;
#pragma unroll
    for (int qq = 0; qq < 4; ++qq)
        va[qq] = ok ? *(const float4*)&agg[node * 64 + qq * CH_IF + grp * 4] : z4;

    f32x4 acc[4];
#pragma unroll
    for (int t = 0; t < 4; ++t) acc[t] = (f32x4){0.f, 0.f, 0.f, 0.f};

    int arow = (wid << 4) + (lane & 15);
    int kfrag = (lane >> 4) * 8;
    const unsigned short* Abase = &A_lds[arow * AST + kfrag];
    const bf16x8* Bbase = (const bf16x8*)Wf + lane;

#pragma unroll
    for (int chunk = 0; chunk < 8; ++chunk) {
        const float4 v4 = (chunk < 4) ? vx[chunk] : va[chunk - 4];
        {
            float vv[4] = {v4.x, v4.y, v4.z, v4.w};
            unsigned short* Arow = &A_lds[n * AST];
#pragma unroll
            for (int jj = 0; jj < 4; ++jj) write_feat(Arow, grp * 4 + jj, vv[jj]);
        }
        __syncthreads();
        {
#pragma unroll
            for (int s = 0; s < 5; ++s) {
                bf16x4 alo = *(const bf16x4*)(Abase + s * 32);
                bf16x4 ahi = *(const bf16x4*)(Abase + s * 32 + 4);
                bf16x8 a = __builtin_shufflevector(alo, ahi, 0, 1, 2, 3, 4, 5, 6, 7);
#pragma unroll
                for (int t = 0; t < 4; ++t) {
                    bf16x8 b = Bbase[((chunk * 5 + s) * 4 + t) * 64];
                    acc[t] = __builtin_amdgcn_mfma_f32_16x16x32_bf16(a, b, acc[t], 0, 0, 0);
                }
            }
        }
        __syncthreads();
    }

#pragma unroll
    for (int t = 0; t < 4; ++t) {
#pragma unroll
        for (int r = 0; r < 4; ++r) {
            int nd = nbase + (wid << 4) + (lane >> 4) * 4 + r;
            if (nd < N_NODES) out[nd * 64 + t * 16 + (lane & 15)] = acc[t][r];
        }
    }
}

extern "C" void kernel_launch(void* const* d_in, const int* in_sizes, int n_in,
                              void* d_out, int out_size, void* d_ws, size_t ws_size,
                              hipStream_t stream) {
    const float* x   = (const float*)d_in[0];
    const float* bwl = (const float*)d_in[1];
    const float* swl = (const float*)d_in[2];
    const float* bwc = (const float*)d_in[3];
    const float* swc = (const float*)d_in[4];
    const int*   ei  = (const int*)d_in[5];
    float* out = (float*)d_out;

    float* ws = (float*)d_ws;
    float* dinv = ws + OFF_DINV;
    int* rowptr = (int*)(ws + OFF_ROWPTR);
    int* rowend = (int*)(ws + OFF_ROWEND);
    unsigned short* Wf = (unsigned short*)(ws + OFF_WT);
    int* bf = (int*)(ws + OFF_BF);
    int* csr = (int*)(ws + OFF_CSR);
    unsigned short* xh = (unsigned short*)(ws + OFF_XH);

    const bool has_csr = ws_size >= (size_t)FIXED_SLOTS * sizeof(float);
    const bool has_xh  = ws_size >= (size_t)FIXED2 * sizeof(float);
    const size_t big_base = has_xh ? (size_t)FIXED2 : (size_t)FIXED_SLOTS;
    const bool big_in_ws = ws_size >= (big_base + (size_t)AGG_ELEMS) * sizeof(float);
    float* bigbuf = (has_csr && big_in_ws) ? (ws + big_base) : out;
    int2* pairs = (int2*)bigbuf;   // dead before any out write (consumed by bucket_build)
    float* agg = bigbuf;           // used only by unfused fallback paths

    if (has_csr) {
        wprep_kernel<<<(WF_U16 + 255) / 256, 256, 0, stream>>>(bwl, swl, bwc, swc, Wf, bf);
        bucket_bin_kernel<<<(N_EDGES + EPB - 1) / EPB, 256, 0, stream>>>(ei, bf, pairs, x, xh);
        bucket_build_kernel<<<NBUCK_USED, BUCK_N, 0, stream>>>(pairs, bf, rowptr, rowend, dinv, csr);
        if (has_xh) {
            kan_fused_kernel<<<(N_NODES + NB - 1) / NB, NTHR, 0, stream>>>(
                x, xh, csr, rowptr, rowend, dinv, Wf, out);
        } else {
            gather_kernel<<<(N_NODES * 64 + 255) / 256, 256, 0, stream>>>(x, csr, rowptr, rowend, dinv, agg);
            kan_mfma_kernel<<<(N_NODES + NB - 1) / NB, NTHR, 0, stream>>>(x, agg, Wf, out);
        }
    } else {
        float* deg = dinv;
        hipMemsetAsync(deg, 0, (size_t)NODES_PAD * sizeof(float), stream);
        deg_kernel<<<(N_EDGES + 255) / 256, 256, 0, stream>>>(ei, deg);
        dinv_kernel<<<(N_NODES + 255) / 256, 256, 0, stream>>>(deg);
        hipMemsetAsync(agg, 0, (size_t)AGG_ELEMS * sizeof(float), stream);
        long long scatter_threads = (long long)N_EDGES * 64;
        int scatter_blocks = (int)((scatter_threads + 255) / 256);
        scatter_kernel<<<scatter_blocks, 256, 0, stream>>>(x, ei, deg, agg);
        wprep_kernel<<<(WF_U16 + 255) / 256, 256, 0, stream>>>(bwl, swl, bwc, swc, Wf, (int*)0);
        kan_mfma_kernel<<<(N_NODES + NB - 1) / NB, NTHR, 0, stream>>>(x, agg, Wf, out);
    }
}

// Round 23
// 154.180 us; speedup vs baseline: 1.1765x; 1.1765x over previous
//
#include <hip/hip_runtime.h>
#include <math.h>

#define N_NODES 100000
#define N_EDGES 1600000
#define IN_F 64
#define OUT_F 64

// KAN GEMM K layout: k = (path*64 + i)*10 + c; c=0..7 spline bases, c=8 silu,
// c=9 zero pad. K'=1280. Chunk = 16 in-feats = 160 k = 5 MFMA K-steps of 32.
#define K_SLOT 10
#define CH_IF 16
#define AST 172            // A_lds row stride in bf16; bank period 16
#define AGH 33             // agg_lds row stride in u32 (bf16x2); 33%32==1
#define NB 64              // nodes per block (kan)
#define NTHR 256
#define EMAXW 448          // per-wave csr slice capacity (mean 256, +12 sigma)

// bucketed CSR build (fixed capacity)
#define NBUCK 256
#define NBUCK_USED 196
#define BSH 9
#define BCAP 9728          // mean 8192 + 17 sigma
#define BUCK_N 512
#define EPT 8
#define EPB 2048

// ws layout (f32 slots)
#define NODES_PAD 100352
#define WF_U16 (8 * 20 * 512)
#define WG_SLOTS (WF_U16 / 2)
#define CSR_CAP (NBUCK_USED * BCAP)
#define OFF_DINV 0
#define OFF_ROWPTR (OFF_DINV + NODES_PAD)
#define OFF_ROWEND (OFF_ROWPTR + NODES_PAD)
#define OFF_WT (OFF_ROWEND + NODES_PAD)
#define OFF_BF (OFF_WT + WG_SLOTS)
#define OFF_CSR (OFF_BF + 256)
#define FIXED_SLOTS (OFF_CSR + CSR_CAP)
#define XH_SLOTS (N_NODES * IN_F / 2)
#define OFF_XH FIXED_SLOTS
#define FIXED2 (FIXED_SLOTS + XH_SLOTS)
#define AGG_ELEMS (N_NODES * IN_F)

typedef __attribute__((ext_vector_type(8))) short bf16x8;
typedef __attribute__((ext_vector_type(4))) short bf16x4;
typedef __attribute__((ext_vector_type(4))) float f32x4;

__device__ __forceinline__ unsigned int bf16_rne(float v) {
    unsigned int u = __float_as_uint(v);
    u += 0x7FFFu + ((u >> 16) & 1u);
    return u >> 16;
}

// ---- bin edges: LDS counting-sort by bucket -> coalesced pairs write-out ----
__global__ __launch_bounds__(256)
void bucket_bin_kernel(const int* __restrict__ ei, int* __restrict__ bf,
                       int2* __restrict__ pairs,
                       const float* __restrict__ x, unsigned short* __restrict__ xh) {
    __shared__ int lh[NBUCK];      // per-bucket count
    __shared__ int lbs[NBUCK];     // scan -> local exclusive base
    __shared__ int lgb[NBUCK];     // global base per bucket
    __shared__ int2 spair[EPB];    // staged pairs (sorted by bucket)
    __shared__ int  sdst[EPB];     // global dest per staged slot
    int t = threadIdx.x;
    lh[t] = 0;
    __syncthreads();
    int e0 = blockIdx.x * EPB;
    int nE = N_EDGES - e0; if (nE > EPB) nE = EPB; if (nE < 0) nE = 0;
    int d[EPT], s[EPT], lp[EPT];
#pragma unroll
    for (int k = 0; k < EPT; ++k) {
        int idx = k * 256 + t;
        bool ok = idx < nE;
        int e = e0 + idx;
        d[k] = ok ? ei[N_EDGES + e] : -1;
        s[k] = ok ? ei[e] : 0;
        lp[k] = ok ? atomicAdd(&lh[d[k] >> BSH], 1) : 0;
    }
    __syncthreads();
    int v = lh[t];
    lbs[t] = v;
    __syncthreads();
    for (int off = 1; off < NBUCK; off <<= 1) {
        int add = (t >= off) ? lbs[t - off] : 0;
        __syncthreads();
        lbs[t] += add;
        __syncthreads();
    }
    int excl = lbs[t] - v;
    if (v) {
        int r = atomicAdd(&bf[t], v);
        int cap = (t + 1) * BCAP - v;
        lgb[t] = r > cap ? cap : r;   // defensive clamp (never triggers at 17 sigma)
    }
    __syncthreads();
    lbs[t] = excl;
    __syncthreads();
#pragma unroll
    for (int k = 0; k < EPT; ++k) {
        if (d[k] >= 0) {
            int b = d[k] >> BSH;
            int sp = lbs[b] + lp[k];
            spair[sp] = make_int2(d[k], s[k]);
            sdst[sp] = lgb[b] + lp[k];
        }
    }
    __syncthreads();
    for (int p = t; p < nE; p += 256) pairs[sdst[p]] = spair[p];

    // merged xprep: x -> bf16 copy (grid-stride)
    int total = gridDim.x * 256;
    for (int i = blockIdx.x * 256 + t; i * 4 < N_NODES * IN_F; i += total) {
        float4 vv = *(const float4*)&x[i * 4];
        uint2 u;
        u.x = bf16_rne(vv.x) | (bf16_rne(vv.y) << 16);
        u.y = bf16_rne(vv.z) | (bf16_rne(vv.w) << 16);
        *(uint2*)&xh[i * 4] = u;
    }
}

// one block per bucket: local deg hist, scan -> rowptr/rowend/dinv, csr fill
__global__ __launch_bounds__(BUCK_N)
void bucket_build_kernel(const int2* __restrict__ pairs, const int* __restrict__ bf,
                         int* __restrict__ rowptr, int* __restrict__ rowend,
                         float* __restrict__ dinv, int* __restrict__ csr) {
    __shared__ int ldeg[BUCK_N];
    __shared__ int sb[BUCK_N];
    __shared__ int lpos[BUCK_N];
    int t = threadIdx.x;
    int b = blockIdx.x;
    int base = b * BCAP;
    int cnt = bf[b] - base;
    if (cnt > BCAP) cnt = BCAP;
    ldeg[t] = 0;
    __syncthreads();
    for (int j = t; j < cnt; j += BUCK_N) atomicAdd(&ldeg[pairs[base + j].x & (BUCK_N - 1)], 1);
    __syncthreads();
    int v = ldeg[t];
    sb[t] = v;
    __syncthreads();
    for (int off = 1; off < BUCK_N; off <<= 1) {
        int add = (t >= off) ? sb[t - off] : 0;
        __syncthreads();
        sb[t] += add;
        __syncthreads();
    }
    int excl = sb[t] - v;
    int node = (b << BSH) + t;
    if (node < N_NODES) {
        rowptr[node] = base + excl;
        rowend[node] = base + excl + v;
        dinv[node] = (v > 0) ? rsqrtf((float)v) : 0.0f;
    }
    lpos[t] = base + excl;
    __syncthreads();
    for (int j = t; j < cnt; j += BUCK_N) {
        int2 p = pairs[base + j];
        int pos = atomicAdd(&lpos[p.x & (BUCK_N - 1)], 1);
        csr[pos] = p.y;
    }
}

// gather (f32 x): fallback when ws can't hold xh
__global__ __launch_bounds__(256)
void gather_kernel(const float* __restrict__ x, const int* __restrict__ csr,
                   const int* __restrict__ rowptr, const int* __restrict__ rowend,
                   const float* __restrict__ dinv, float* __restrict__ agg) {
    int wid = (int)((blockIdx.x * 256 + threadIdx.x) >> 6);
    int lane = threadIdx.x & 63;
    if (wid >= N_NODES) return;
    int start = rowptr[wid];
    int end = rowend[wid];
    float acc = 0.0f;
    int j = start;
    for (; j + 3 < end; j += 4) {
        int s0 = csr[j], s1 = csr[j + 1], s2 = csr[j + 2], s3 = csr[j + 3];
        float a0 = x[s0 * 64 + lane] * dinv[s0];
        float a1 = x[s1 * 64 + lane] * dinv[s1];
        float a2 = x[s2 * 64 + lane] * dinv[s2];
        float a3 = x[s3 * 64 + lane] * dinv[s3];
        acc += a0 + a1 + a2 + a3;
    }
    for (; j < end; ++j) {
        int s = csr[j];
        acc += x[s * 64 + lane] * dinv[s];
    }
    agg[wid * 64 + lane] = acc * dinv[wid];
}

// ---- fallback (ws too small): f32 atomic scatter ----
__global__ void deg_kernel(const int* __restrict__ ei, float* __restrict__ deg) {
    int e = blockIdx.x * blockDim.x + threadIdx.x;
    if (e < N_EDGES) atomicAdd(&deg[ei[N_EDGES + e]], 1.0f);
}
__global__ void dinv_kernel(float* __restrict__ deg) {
    int n = blockIdx.x * blockDim.x + threadIdx.x;
    if (n < N_NODES) {
        float d = deg[n];
        deg[n] = (d > 0.0f) ? rsqrtf(d) : 0.0f;
    }
}
__global__ void scatter_kernel(const float* __restrict__ x, const int* __restrict__ ei,
                               const float* __restrict__ dinv, float* __restrict__ agg) {
    long long gtid = (long long)blockIdx.x * blockDim.x + threadIdx.x;
    int wid = (int)(gtid >> 6);
    int lane = threadIdx.x & 63;
    if (wid >= N_EDGES) return;
    int s = ei[wid];
    int d = ei[N_EDGES + wid];
    float c = dinv[s] * dinv[d];
    atomicAdd(&agg[d * 64 + lane], x[s * 64 + lane] * c);
}

// Wf in MFMA fragment order + bf cursor init (bf may be null in fallback path)
__global__ void wprep_kernel(const float* __restrict__ bwl, const float* __restrict__ swl,
                             const float* __restrict__ bwc, const float* __restrict__ swc,
                             unsigned short* __restrict__ Wf, int* __restrict__ bf) {
    int gid = blockIdx.x * blockDim.x + threadIdx.x;
    if (bf && gid < NBUCK) bf[gid] = gid * BCAP;
    if (gid >= WF_U16) return;
    int fr = gid >> 9;
    int lj = gid & 511;
    int lane = lj >> 3, j = lj & 7;
    int ch = fr / 20, r2 = fr - ch * 20;
    int s = r2 >> 2, t = r2 & 3;
    int o = t * 16 + (lane & 15);
    int kk = ((lane >> 4) << 3) + s * 32 + j;
    int iL = kk / K_SLOT, c = kk - iL * K_SLOT;
    int i = (ch & 3) * CH_IF + iL;
    int path = ch >> 2;
    const float* bw = path ? bwc : bwl;
    const float* sw = path ? swc : swl;
    float v = 0.0f;
    if (c == 8) v = bw[o * IN_F + i];
    else if (c < 8) v = sw[o * 512 + i * 8 + c];
    Wf[gid] = (unsigned short)bf16_rne(v);
}

// shared feature-write helper
__device__ __forceinline__ void write_feat(unsigned short* Arow, int iL, float v) {
    unsigned int* Au = (unsigned int*)(Arow + iL * K_SLOT);
    float sig = __builtin_amdgcn_rcpf(1.0f + __expf(-v));
    Au[0] = 0u; Au[1] = 0u; Au[2] = 0u; Au[3] = 0u;
    Au[4] = bf16_rne(v * sig);
    float s5 = (v + 2.2f) * 2.5f;
    float fm = floorf(s5);
    int m = (int)fm;
    if (m >= 0 && m <= 10) {
        float t = s5 - fm;
        float omt = 1.0f - t;
        float t2 = t * t, t3 = t2 * t;
        float n0 = omt * omt * omt * (1.0f / 6.0f);
        float n3 = t3 * (1.0f / 6.0f);
        float n1 = 0.66666666f - t2 + 0.5f * t3;
        float n2 = 1.0f - n0 - n1 - n3;
        unsigned short* As = Arow + iL * K_SLOT;
        if (m >= 3)           As[m - 3] = (unsigned short)bf16_rne(n0);
        if (m >= 2 && m <= 9) As[m - 2] = (unsigned short)bf16_rne(n1);
        if (m >= 1 && m <= 8) As[m - 1] = (unsigned short)bf16_rne(n2);
        if (m <= 7)           As[m]     = (unsigned short)bf16_rne(n3);
    }
}

// FUSED gather + MFMA KAN (R20 form, restored): barrier-free, wave-self-contained.
// Wave's contiguous csr slice staged to LDS first (one coalesced read) -> gather
// has single-level global dependency, 16-deep unroll. Parity-staggered phases.
// Chunk accumulation order is 0..7 in both parities -> bit-identical output.
__global__ __launch_bounds__(NTHR, 4)
void kan_fused_kernel(const float* __restrict__ x, const unsigned short* __restrict__ xh,
                      const int* __restrict__ csr, const int* __restrict__ rowptr,
                      const int* __restrict__ rowend, const float* __restrict__ dinv,
                      const unsigned short* __restrict__ Wf, float* __restrict__ out) {
    __shared__ __align__(16) unsigned short A_lds[NB * AST];   // 22016 B
    __shared__ unsigned int agg_lds[NB * AGH];                 // 8448 B
    __shared__ int csr_lds[4 * EMAXW];                         // 7168 B

    int tid = threadIdx.x;
    int nbase = blockIdx.x * NB;
    int wid = tid >> 6;
    int lane = tid & 63;
    int nloc0 = (wid << 4) + (lane & 15);
    int q = lane >> 4;
    int node0 = nbase + nloc0;
    bool ok0 = node0 < N_NODES;

    const float4 z4 = make_float4(0.f, 0.f, 0.f, 0.f);
    float4 vx[4];
#pragma unroll
    for (int c = 0; c < 4; ++c)
        vx[c] = ok0 ? *(const float4*)&x[node0 * 64 + c * CH_IF + q * 4] : z4;

    // ---- stage wave's contiguous csr slice into LDS (wave-local, no barrier)
    int wn0 = nbase + (wid << 4);
    int s0w = 0, slenw = 0;
    int* wcsr = &csr_lds[wid * EMAXW];
    if (wn0 < N_NODES) {
        int wnL = wn0 + 15;
        if (wnL >= N_NODES) wnL = N_NODES - 1;
        s0w = rowptr[wn0];
        slenw = rowend[wnL] - s0w;
        int cap = slenw < EMAXW ? slenw : EMAXW;
        for (int i = lane; i < cap; i += 64) wcsr[i] = csr[s0w + i];
    }

    f32x4 acc[4];
#pragma unroll
    for (int t = 0; t < 4; ++t) acc[t] = (f32x4){0.f, 0.f, 0.f, 0.f};

    int kfrag = (lane >> 4) * 8;
    const unsigned short* Abase = &A_lds[nloc0 * AST + kfrag];
    unsigned short* Arow = &A_lds[nloc0 * AST];
    const bf16x8* Bbase = (const bf16x8*)Wf + lane;

    auto do_chunk = [&](int chunk) {
        float vv[4];
        if (chunk < 4) {
            vv[0] = vx[chunk].x; vv[1] = vx[chunk].y; vv[2] = vx[chunk].z; vv[3] = vx[chunk].w;
        } else {
            int b2 = (chunk - 4) * 8 + q * 2;
            unsigned u0 = agg_lds[nloc0 * AGH + b2];
            unsigned u1 = agg_lds[nloc0 * AGH + b2 + 1];
            vv[0] = __uint_as_float(u0 << 16);
            vv[1] = __uint_as_float(u0 & 0xFFFF0000u);
            vv[2] = __uint_as_float(u1 << 16);
            vv[3] = __uint_as_float(u1 & 0xFFFF0000u);
        }
#pragma unroll
        for (int jj = 0; jj < 4; ++jj) write_feat(Arow, q * 4 + jj, vv[jj]);
#pragma unroll
        for (int s = 0; s < 5; ++s) {
            bf16x4 alo = *(const bf16x4*)(Abase + s * 32);
            bf16x4 ahi = *(const bf16x4*)(Abase + s * 32 + 4);
            bf16x8 a = __builtin_shufflevector(alo, ahi, 0, 1, 2, 3, 4, 5, 6, 7);
#pragma unroll
            for (int t = 0; t < 4; ++t) {
                bf16x8 b = Bbase[((chunk * 5 + s) * 4 + t) * 64];
                acc[t] = __builtin_amdgcn_mfma_f32_16x16x32_bf16(a, b, acc[t], 0, 0, 0);
            }
        }
    };

    auto do_gather = [&]() {
        int half = lane >> 5;
        int l = lane & 31;
        const unsigned int* xh32 = (const unsigned int*)xh;
        for (int p = 0; p < 8; ++p) {
            int nloc = (wid << 4) + (p << 1) + half;
            int nd = nbase + nloc;
            float ax = 0.f, ay = 0.f, dn = 0.f;
            if (nd < N_NODES) {
                dn = dinv[nd];
                int j = rowptr[nd] - s0w;
                int end = rowend[nd] - s0w;
                if (end <= EMAXW) {
                    // fast path: indices from LDS -> single-level global dependency
                    for (; j + 15 < end; j += 16) {
                        int sa[16]; unsigned ua[16]; float da[16];
#pragma unroll
                        for (int k = 0; k < 16; ++k) sa[k] = wcsr[j + k];
#pragma unroll
                        for (int k = 0; k < 16; ++k) ua[k] = xh32[sa[k] * 32 + l];
#pragma unroll
                        for (int k = 0; k < 16; ++k) da[k] = dinv[sa[k]];
#pragma unroll
                        for (int k = 0; k < 16; ++k) {
                            ax += __uint_as_float(ua[k] << 16) * da[k];
                            ay += __uint_as_float(ua[k] & 0xFFFF0000u) * da[k];
                        }
                    }
                    for (; j + 3 < end; j += 4) {
                        int s0 = wcsr[j], s1 = wcsr[j + 1], s2 = wcsr[j + 2], s3 = wcsr[j + 3];
                        unsigned u0 = xh32[s0 * 32 + l], u1 = xh32[s1 * 32 + l];
                        unsigned u2 = xh32[s2 * 32 + l], u3 = xh32[s3 * 32 + l];
                        float d0 = dinv[s0], d1 = dinv[s1], d2 = dinv[s2], d3 = dinv[s3];
                        ax += __uint_as_float(u0 << 16) * d0 + __uint_as_float(u1 << 16) * d1
                            + __uint_as_float(u2 << 16) * d2 + __uint_as_float(u3 << 16) * d3;
                        ay += __uint_as_float(u0 & 0xFFFF0000u) * d0 + __uint_as_float(u1 & 0xFFFF0000u) * d1
                            + __uint_as_float(u2 & 0xFFFF0000u) * d2 + __uint_as_float(u3 & 0xFFFF0000u) * d3;
                    }
                    for (; j < end; ++j) {
                        int s = wcsr[j];
                        unsigned u = xh32[s * 32 + l];
                        float d = dinv[s];
                        ax += __uint_as_float(u << 16) * d;
                        ay += __uint_as_float(u & 0xFFFF0000u) * d;
                    }
                } else {
                    // overflow fallback: direct global csr (rare; preserves order)
                    for (int g = rowptr[nd]; g < rowend[nd]; ++g) {
                        int s = csr[g];
                        unsigned u = xh32[s * 32 + l];
                        float d = dinv[s];
                        ax += __uint_as_float(u << 16) * d;
                        ay += __uint_as_float(u & 0xFFFF0000u) * d;
                    }
                }
            }
            agg_lds[nloc * AGH + l] = bf16_rne(ax * dn) | (bf16_rne(ay * dn) << 16);
        }
    };

    if ((blockIdx.x & 1) == 0) {
#pragma unroll
        for (int c = 0; c < 4; ++c) do_chunk(c);
        do_gather();
#pragma unroll
        for (int c = 4; c < 8; ++c) do_chunk(c);
    } else {
        do_gather();
#pragma unroll
        for (int c = 0; c < 8; ++c) do_chunk(c);
    }

#pragma unroll
    for (int t = 0; t < 4; ++t) {
#pragma unroll
        for (int r = 0; r < 4; ++r) {
            int nd = nbase + (wid << 4) + (lane >> 4) * 4 + r;
            if (nd < N_NODES) out[nd * 64 + t * 16 + (lane & 15)] = acc[t][r];
        }
    }
}

// unfused MFMA KAN (fallback when no xh): reads agg from global; keeps barriers
__global__ __launch_bounds__(NTHR, 8)
void kan_mfma_kernel(const float* __restrict__ x, const float* __restrict__ agg,
                     const unsigned short* __restrict__ Wf, float* __restrict__ out) {
    __shared__ __align__(16) unsigned short A_lds[NB * AST];

    int tid = threadIdx.x;
    int nbase = blockIdx.x * NB;
    int wid = tid >> 6;
    int lane = tid & 63;
    int n = tid & (NB - 1);
    int grp = wid;
    int node = nbase + n;
    bool ok = node < N_NODES;
    const float4 z4 = make_float4(0.f, 0.f, 0.f, 0.f);
    float4 vx[4], va[4];
#pragma unroll
    for (int qq = 0; qq < 4; ++qq)
        vx[qq] = ok ? *(const float4*)&x[node * 64 + qq * CH_IF + grp * 4] : z4;
#pragma unroll
    for (int qq = 0; qq < 4; ++qq)
        va[qq] = ok ? *(const float4*)&agg[node * 64 + qq * CH_IF + grp * 4] : z4;

    f32x4 acc[4];
#pragma unroll
    for (int t = 0; t < 4; ++t) acc[t] = (f32x4){0.f, 0.f, 0.f, 0.f};

    int arow = (wid << 4) + (lane & 15);
    int kfrag = (lane >> 4) * 8;
    const unsigned short* Abase = &A_lds[arow * AST + kfrag];
    const bf16x8* Bbase = (const bf16x8*)Wf + lane;

#pragma unroll
    for (int chunk = 0; chunk < 8; ++chunk) {
        const float4 v4 = (chunk < 4) ? vx[chunk] : va[chunk - 4];
        {
            float vv[4] = {v4.x, v4.y, v4.z, v4.w};
            unsigned short* Arow = &A_lds[n * AST];
#pragma unroll
            for (int jj = 0; jj < 4; ++jj) write_feat(Arow, grp * 4 + jj, vv[jj]);
        }
        __syncthreads();
        {
#pragma unroll
            for (int s = 0; s < 5; ++s) {
                bf16x4 alo = *(const bf16x4*)(Abase + s * 32);
                bf16x4 ahi = *(const bf16x4*)(Abase + s * 32 + 4);
                bf16x8 a = __builtin_shufflevector(alo, ahi, 0, 1, 2, 3, 4, 5, 6, 7);
#pragma unroll
                for (int t = 0; t < 4; ++t) {
                    bf16x8 b = Bbase[((chunk * 5 + s) * 4 + t) * 64];
                    acc[t] = __builtin_amdgcn_mfma_f32_16x16x32_bf16(a, b, acc[t], 0, 0, 0);
                }
            }
        }
        __syncthreads();
    }

#pragma unroll
    for (int t = 0; t < 4; ++t) {
#pragma unroll
        for (int r = 0; r < 4; ++r) {
            int nd = nbase + (wid << 4) + (lane >> 4) * 4 + r;
            if (nd < N_NODES) out[nd * 64 + t * 16 + (lane & 15)] = acc[t][r];
        }
    }
}

extern "C" void kernel_launch(void* const* d_in, const int* in_sizes, int n_in,
                              void* d_out, int out_size, void* d_ws, size_t ws_size,
                              hipStream_t stream) {
    const float* x   = (const float*)d_in[0];
    const float* bwl = (const float*)d_in[1];
    const float* swl = (const float*)d_in[2];
    const float* bwc = (const float*)d_in[3];
    const float* swc = (const float*)d_in[4];
    const int*   ei  = (const int*)d_in[5];
    float* out = (float*)d_out;

    float* ws = (float*)d_ws;
    float* dinv = ws + OFF_DINV;
    int* rowptr = (int*)(ws + OFF_ROWPTR);
    int* rowend = (int*)(ws + OFF_ROWEND);
    unsigned short* Wf = (unsigned short*)(ws + OFF_WT);
    int* bf = (int*)(ws + OFF_BF);
    int* csr = (int*)(ws + OFF_CSR);
    unsigned short* xh = (unsigned short*)(ws + OFF_XH);

    const bool has_csr = ws_size >= (size_t)FIXED_SLOTS * sizeof(float);
    const bool has_xh  = ws_size >= (size_t)FIXED2 * sizeof(float);
    const size_t big_base = has_xh ? (size_t)FIXED2 : (size_t)FIXED_SLOTS;
    const bool big_in_ws = ws_size >= (big_base + (size_t)AGG_ELEMS) * sizeof(float);
    float* bigbuf = (has_csr && big_in_ws) ? (ws + big_base) : out;
    int2* pairs = (int2*)bigbuf;   // dead before any out write (consumed by bucket_build)
    float* agg = bigbuf;           // used only by unfused fallback paths

    if (has_csr) {
        wprep_kernel<<<(WF_U16 + 255) / 256, 256, 0, stream>>>(bwl, swl, bwc, swc, Wf, bf);
        bucket_bin_kernel<<<(N_EDGES + EPB - 1) / EPB, 256, 0, stream>>>(ei, bf, pairs, x, xh);
        bucket_build_kernel<<<NBUCK_USED, BUCK_N, 0, stream>>>(pairs, bf, rowptr, rowend, dinv, csr);
        if (has_xh) {
            kan_fused_kernel<<<(N_NODES + NB - 1) / NB, NTHR, 0, stream>>>(
                x, xh, csr, rowptr, rowend, dinv, Wf, out);
        } else {
            gather_kernel<<<(N_NODES * 64 + 255) / 256, 256, 0, stream>>>(x, csr, rowptr, rowend, dinv, agg);
            kan_mfma_kernel<<<(N_NODES + NB - 1) / NB, NTHR, 0, stream>>>(x, agg, Wf, out);
        }
    } else {
        float* deg = dinv;
        hipMemsetAsync(deg, 0, (size_t)NODES_PAD * sizeof(float), stream);
        deg_kernel<<<(N_EDGES + 255) / 256, 256, 0, stream>>>(ei, deg);
        dinv_kernel<<<(N_NODES + 255) / 256, 256, 0, stream>>>(deg);
        hipMemsetAsync(agg, 0, (size_t)AGG_ELEMS * sizeof(float), stream);
        long long scatter_threads = (long long)N_EDGES * 64;
        int scatter_blocks = (int)((scatter_threads + 255) / 256);
        scatter_kernel<<<scatter_blocks, 256, 0, stream>>>(x, ei, deg, agg);
        wprep_kernel<<<(WF_U16 + 255) / 256, 256, 0, stream>>>(bwl, swl, bwc, swc, Wf, (int*)0);
        kan_mfma_kernel<<<(N_NODES + NB - 1) / NB, NTHR, 0, stream>>>(x, agg, Wf, out);
    }
}

// Round 24
// 149.941 us; speedup vs baseline: 1.2098x; 1.0283x over previous
//
#include <hip/hip_runtime.h>
#include <math.h>

#define N_NODES 100000
#define N_EDGES 1600000
#define IN_F 64
#define OUT_F 64

// KAN GEMM K layout: k = (path*64 + i)*10 + c; c=0..7 spline bases, c=8 silu,
// c=9 zero pad. K'=1280. Chunk = 16 in-feats = 160 k = 5 MFMA K-steps of 32.
#define K_SLOT 10
#define CH_IF 16
#define AST 172            // A_lds row stride in bf16; bank period 16
#define AGH 33             // agg_lds row stride in u32 (bf16x2); 33%32==1
#define NB 64              // nodes per block (kan)
#define NTHR 256
#define EMAXW 448          // per-wave csr slice capacity (mean 256, +12 sigma)

// bucketed CSR build (fixed capacity)
#define NBUCK 256
#define NBUCK_USED 196
#define BSH 9
#define BCAP 9728          // mean 8192 + 17 sigma
#define BUCK_N 512
#define EPT 8
#define EPB 2048

// ws layout (f32 slots)
#define NODES_PAD 100352
#define WF_U16 (8 * 20 * 512)
#define WG_SLOTS (WF_U16 / 2)
#define CSR_CAP (NBUCK_USED * BCAP)
#define OFF_DINV 0
#define OFF_ROWPTR (OFF_DINV + NODES_PAD)
#define OFF_ROWEND (OFF_ROWPTR + NODES_PAD)
#define OFF_WT (OFF_ROWEND + NODES_PAD)
#define OFF_BF (OFF_WT + WG_SLOTS)
#define OFF_CSR (OFF_BF + 256)
#define FIXED_SLOTS (OFF_CSR + CSR_CAP)
#define XH_SLOTS (N_NODES * IN_F / 2)
#define OFF_XH FIXED_SLOTS
#define FIXED2 (FIXED_SLOTS + XH_SLOTS)
#define AGG_ELEMS (N_NODES * IN_F)

typedef __attribute__((ext_vector_type(8))) short bf16x8;
typedef __attribute__((ext_vector_type(4))) short bf16x4;
typedef __attribute__((ext_vector_type(4))) float f32x4;

__device__ __forceinline__ unsigned int bf16_rne(float v) {
    unsigned int u = __float_as_uint(v);
    u += 0x7FFFu + ((u >> 16) & 1u);
    return u >> 16;
}

// ---- bin edges: LDS counting-sort by bucket -> coalesced pairs write-out ----
__global__ __launch_bounds__(256)
void bucket_bin_kernel(const int* __restrict__ ei, int* __restrict__ bf,
                       int2* __restrict__ pairs) {
    __shared__ int lh[NBUCK];      // per-bucket count
    __shared__ int lbs[NBUCK];     // scan -> local exclusive base
    __shared__ int lgb[NBUCK];     // global base per bucket
    __shared__ int2 spair[EPB];    // staged pairs (sorted by bucket)
    __shared__ int  sdst[EPB];     // global dest per staged slot
    int t = threadIdx.x;
    lh[t] = 0;
    __syncthreads();
    int e0 = blockIdx.x * EPB;
    int nE = N_EDGES - e0; if (nE > EPB) nE = EPB; if (nE < 0) nE = 0;
    int d[EPT], s[EPT], lp[EPT];
#pragma unroll
    for (int k = 0; k < EPT; ++k) {
        int idx = k * 256 + t;
        bool ok = idx < nE;
        int e = e0 + idx;
        d[k] = ok ? ei[N_EDGES + e] : -1;
        s[k] = ok ? ei[e] : 0;
        lp[k] = ok ? atomicAdd(&lh[d[k] >> BSH], 1) : 0;
    }
    __syncthreads();
    int v = lh[t];
    lbs[t] = v;
    __syncthreads();
    for (int off = 1; off < NBUCK; off <<= 1) {
        int add = (t >= off) ? lbs[t - off] : 0;
        __syncthreads();
        lbs[t] += add;
        __syncthreads();
    }
    int excl = lbs[t] - v;
    if (v) {
        int r = atomicAdd(&bf[t], v);
        int cap = (t + 1) * BCAP - v;
        lgb[t] = r > cap ? cap : r;   // defensive clamp (never triggers at 17 sigma)
    }
    __syncthreads();
    lbs[t] = excl;
    __syncthreads();
#pragma unroll
    for (int k = 0; k < EPT; ++k) {
        if (d[k] >= 0) {
            int b = d[k] >> BSH;
            int sp = lbs[b] + lp[k];
            spair[sp] = make_int2(d[k], s[k]);
            sdst[sp] = lgb[b] + lp[k];
        }
    }
    __syncthreads();
    for (int p = t; p < nE; p += 256) pairs[sdst[p]] = spair[p];
}

// one block per bucket: local deg hist, scan -> rowptr/rowend/dinv, csr fill
__global__ __launch_bounds__(BUCK_N)
void bucket_build_kernel(const int2* __restrict__ pairs, const int* __restrict__ bf,
                         int* __restrict__ rowptr, int* __restrict__ rowend,
                         float* __restrict__ dinv, int* __restrict__ csr) {
    __shared__ int ldeg[BUCK_N];
    __shared__ int sb[BUCK_N];
    __shared__ int lpos[BUCK_N];
    int t = threadIdx.x;
    int b = blockIdx.x;
    int base = b * BCAP;
    int cnt = bf[b] - base;
    if (cnt > BCAP) cnt = BCAP;
    ldeg[t] = 0;
    __syncthreads();
    for (int j = t; j < cnt; j += BUCK_N) atomicAdd(&ldeg[pairs[base + j].x & (BUCK_N - 1)], 1);
    __syncthreads();
    int v = ldeg[t];
    sb[t] = v;
    __syncthreads();
    for (int off = 1; off < BUCK_N; off <<= 1) {
        int add = (t >= off) ? sb[t - off] : 0;
        __syncthreads();
        sb[t] += add;
        __syncthreads();
    }
    int excl = sb[t] - v;
    int node = (b << BSH) + t;
    if (node < N_NODES) {
        rowptr[node] = base + excl;
        rowend[node] = base + excl + v;
        dinv[node] = (v > 0) ? rsqrtf((float)v) : 0.0f;
    }
    lpos[t] = base + excl;
    __syncthreads();
    for (int j = t; j < cnt; j += BUCK_N) {
        int2 p = pairs[base + j];
        int pos = atomicAdd(&lpos[p.x & (BUCK_N - 1)], 1);
        csr[pos] = p.y;
    }
}

// xprep (after build): xh[n][f] = bf16(x[n][f] * dinv[n]) — folds src scaling
// into the gathered value, halving random requests per edge in the gather.
__global__ __launch_bounds__(256)
void xprep2_kernel(const float* __restrict__ x, const float* __restrict__ dinv,
                   unsigned short* __restrict__ xh) {
    int i = blockIdx.x * 256 + threadIdx.x;
    if (i * 4 >= N_NODES * IN_F) return;
    int node = i >> 4;                     // (i*4)/64
    float dn = dinv[node];
    float4 v = *(const float4*)&x[i * 4];
    uint2 u;
    u.x = bf16_rne(v.x * dn) | (bf16_rne(v.y * dn) << 16);
    u.y = bf16_rne(v.z * dn) | (bf16_rne(v.w * dn) << 16);
    *(uint2*)&xh[i * 4] = u;
}

// gather (f32 x): fallback when ws can't hold xh
__global__ __launch_bounds__(256)
void gather_kernel(const float* __restrict__ x, const int* __restrict__ csr,
                   const int* __restrict__ rowptr, const int* __restrict__ rowend,
                   const float* __restrict__ dinv, float* __restrict__ agg) {
    int wid = (int)((blockIdx.x * 256 + threadIdx.x) >> 6);
    int lane = threadIdx.x & 63;
    if (wid >= N_NODES) return;
    int start = rowptr[wid];
    int end = rowend[wid];
    float acc = 0.0f;
    int j = start;
    for (; j + 3 < end; j += 4) {
        int s0 = csr[j], s1 = csr[j + 1], s2 = csr[j + 2], s3 = csr[j + 3];
        float a0 = x[s0 * 64 + lane] * dinv[s0];
        float a1 = x[s1 * 64 + lane] * dinv[s1];
        float a2 = x[s2 * 64 + lane] * dinv[s2];
        float a3 = x[s3 * 64 + lane] * dinv[s3];
        acc += a0 + a1 + a2 + a3;
    }
    for (; j < end; ++j) {
        int s = csr[j];
        acc += x[s * 64 + lane] * dinv[s];
    }
    agg[wid * 64 + lane] = acc * dinv[wid];
}

// ---- fallback (ws too small): f32 atomic scatter ----
__global__ void deg_kernel(const int* __restrict__ ei, float* __restrict__ deg) {
    int e = blockIdx.x * blockDim.x + threadIdx.x;
    if (e < N_EDGES) atomicAdd(&deg[ei[N_EDGES + e]], 1.0f);
}
__global__ void dinv_kernel(float* __restrict__ deg) {
    int n = blockIdx.x * blockDim.x + threadIdx.x;
    if (n < N_NODES) {
        float d = deg[n];
        deg[n] = (d > 0.0f) ? rsqrtf(d) : 0.0f;
    }
}
__global__ void scatter_kernel(const float* __restrict__ x, const int* __restrict__ ei,
                               const float* __restrict__ dinv, float* __restrict__ agg) {
    long long gtid = (long long)blockIdx.x * blockDim.x + threadIdx.x;
    int wid = (int)(gtid >> 6);
    int lane = threadIdx.x & 63;
    if (wid >= N_EDGES) return;
    int s = ei[wid];
    int d = ei[N_EDGES + wid];
    float c = dinv[s] * dinv[d];
    atomicAdd(&agg[d * 64 + lane], x[s * 64 + lane] * c);
}

// Wf in MFMA fragment order + bf cursor init (bf may be null in fallback path)
__global__ void wprep_kernel(const float* __restrict__ bwl, const float* __restrict__ swl,
                             const float* __restrict__ bwc, const float* __restrict__ swc,
                             unsigned short* __restrict__ Wf, int* __restrict__ bf) {
    int gid = blockIdx.x * blockDim.x + threadIdx.x;
    if (bf && gid < NBUCK) bf[gid] = gid * BCAP;
    if (gid >= WF_U16) return;
    int fr = gid >> 9;
    int lj = gid & 511;
    int lane = lj >> 3, j = lj & 7;
    int ch = fr / 20, r2 = fr - ch * 20;
    int s = r2 >> 2, t = r2 & 3;
    int o = t * 16 + (lane & 15);
    int kk = ((lane >> 4) << 3) + s * 32 + j;
    int iL = kk / K_SLOT, c = kk - iL * K_SLOT;
    int i = (ch & 3) * CH_IF + iL;
    int path = ch >> 2;
    const float* bw = path ? bwc : bwl;
    const float* sw = path ? swc : swl;
    float v = 0.0f;
    if (c == 8) v = bw[o * IN_F + i];
    else if (c < 8) v = sw[o * 512 + i * 8 + c];
    Wf[gid] = (unsigned short)bf16_rne(v);
}

// shared feature-write helper
__device__ __forceinline__ void write_feat(unsigned short* Arow, int iL, float v) {
    unsigned int* Au = (unsigned int*)(Arow + iL * K_SLOT);
    float sig = __builtin_amdgcn_rcpf(1.0f + __expf(-v));
    Au[0] = 0u; Au[1] = 0u; Au[2] = 0u; Au[3] = 0u;
    Au[4] = bf16_rne(v * sig);
    float s5 = (v + 2.2f) * 2.5f;
    float fm = floorf(s5);
    int m = (int)fm;
    if (m >= 0 && m <= 10) {
        float t = s5 - fm;
        float omt = 1.0f - t;
        float t2 = t * t, t3 = t2 * t;
        float n0 = omt * omt * omt * (1.0f / 6.0f);
        float n3 = t3 * (1.0f / 6.0f);
        float n1 = 0.66666666f - t2 + 0.5f * t3;
        float n2 = 1.0f - n0 - n1 - n3;
        unsigned short* As = Arow + iL * K_SLOT;
        if (m >= 3)           As[m - 3] = (unsigned short)bf16_rne(n0);
        if (m >= 2 && m <= 9) As[m - 2] = (unsigned short)bf16_rne(n1);
        if (m >= 1 && m <= 8) As[m - 1] = (unsigned short)bf16_rne(n2);
        if (m <= 7)           As[m]     = (unsigned short)bf16_rne(n3);
    }
}

// FUSED gather + MFMA KAN: barrier-free, wave-self-contained, csr-LDS-staged,
// parity-staggered. Gather reads ONLY xh (dinv[src] pre-folded) -> 2 random
// line-requests per edge instead of 3.
__global__ __launch_bounds__(NTHR, 4)
void kan_fused_kernel(const float* __restrict__ x, const unsigned short* __restrict__ xh,
                      const int* __restrict__ csr, const int* __restrict__ rowptr,
                      const int* __restrict__ rowend, const float* __restrict__ dinv,
                      const unsigned short* __restrict__ Wf, float* __restrict__ out) {
    __shared__ __align__(16) unsigned short A_lds[NB * AST];   // 22016 B
    __shared__ unsigned int agg_lds[NB * AGH];                 // 8448 B
    __shared__ int csr_lds[4 * EMAXW];                         // 7168 B

    int tid = threadIdx.x;
    int nbase = blockIdx.x * NB;
    int wid = tid >> 6;
    int lane = tid & 63;
    int nloc0 = (wid << 4) + (lane & 15);
    int q = lane >> 4;
    int node0 = nbase + nloc0;
    bool ok0 = node0 < N_NODES;

    const float4 z4 = make_float4(0.f, 0.f, 0.f, 0.f);
    float4 vx[4];
#pragma unroll
    for (int c = 0; c < 4; ++c)
        vx[c] = ok0 ? *(const float4*)&x[node0 * 64 + c * CH_IF + q * 4] : z4;

    // ---- stage wave's contiguous csr slice into LDS (wave-local, no barrier)
    int wn0 = nbase + (wid << 4);
    int s0w = 0, slenw = 0;
    int* wcsr = &csr_lds[wid * EMAXW];
    if (wn0 < N_NODES) {
        int wnL = wn0 + 15;
        if (wnL >= N_NODES) wnL = N_NODES - 1;
        s0w = rowptr[wn0];
        slenw = rowend[wnL] - s0w;
        int cap = slenw < EMAXW ? slenw : EMAXW;
        for (int i = lane; i < cap; i += 64) wcsr[i] = csr[s0w + i];
    }

    f32x4 acc[4];
#pragma unroll
    for (int t = 0; t < 4; ++t) acc[t] = (f32x4){0.f, 0.f, 0.f, 0.f};

    int kfrag = (lane >> 4) * 8;
    const unsigned short* Abase = &A_lds[nloc0 * AST + kfrag];
    unsigned short* Arow = &A_lds[nloc0 * AST];
    const bf16x8* Bbase = (const bf16x8*)Wf + lane;

    auto do_chunk = [&](int chunk) {
        float vv[4];
        if (chunk < 4) {
            vv[0] = vx[chunk].x; vv[1] = vx[chunk].y; vv[2] = vx[chunk].z; vv[3] = vx[chunk].w;
        } else {
            int b2 = (chunk - 4) * 8 + q * 2;
            unsigned u0 = agg_lds[nloc0 * AGH + b2];
            unsigned u1 = agg_lds[nloc0 * AGH + b2 + 1];
            vv[0] = __uint_as_float(u0 << 16);
            vv[1] = __uint_as_float(u0 & 0xFFFF0000u);
            vv[2] = __uint_as_float(u1 << 16);
            vv[3] = __uint_as_float(u1 & 0xFFFF0000u);
        }
#pragma unroll
        for (int jj = 0; jj < 4; ++jj) write_feat(Arow, q * 4 + jj, vv[jj]);
#pragma unroll
        for (int s = 0; s < 5; ++s) {
            bf16x4 alo = *(const bf16x4*)(Abase + s * 32);
            bf16x4 ahi = *(const bf16x4*)(Abase + s * 32 + 4);
            bf16x8 a = __builtin_shufflevector(alo, ahi, 0, 1, 2, 3, 4, 5, 6, 7);
#pragma unroll
            for (int t = 0; t < 4; ++t) {
                bf16x8 b = Bbase[((chunk * 5 + s) * 4 + t) * 64];
                acc[t] = __builtin_amdgcn_mfma_f32_16x16x32_bf16(a, b, acc[t], 0, 0, 0);
            }
        }
    };

    auto do_gather = [&]() {
        int half = lane >> 5;
        int l = lane & 31;
        const unsigned int* xh32 = (const unsigned int*)xh;
        for (int p = 0; p < 8; ++p) {
            int nloc = (wid << 4) + (p << 1) + half;
            int nd = nbase + nloc;
            float ax = 0.f, ay = 0.f, dn = 0.f;
            if (nd < N_NODES) {
                dn = dinv[nd];
                int j = rowptr[nd] - s0w;
                int end = rowend[nd] - s0w;
                if (end <= EMAXW) {
                    // fast path: indices from LDS; values pre-scaled -> 1 load/edge
                    for (; j + 15 < end; j += 16) {
                        int sa[16]; unsigned ua[16];
#pragma unroll
                        for (int k = 0; k < 16; ++k) sa[k] = wcsr[j + k];
#pragma unroll
                        for (int k = 0; k < 16; ++k) ua[k] = xh32[sa[k] * 32 + l];
#pragma unroll
                        for (int k = 0; k < 16; ++k) {
                            ax += __uint_as_float(ua[k] << 16);
                            ay += __uint_as_float(ua[k] & 0xFFFF0000u);
                        }
                    }
                    for (; j + 3 < end; j += 4) {
                        int s0 = wcsr[j], s1 = wcsr[j + 1], s2 = wcsr[j + 2], s3 = wcsr[j + 3];
                        unsigned u0 = xh32[s0 * 32 + l], u1 = xh32[s1 * 32 + l];
                        unsigned u2 = xh32[s2 * 32 + l], u3 = xh32[s3 * 32 + l];
                        ax += __uint_as_float(u0 << 16) + __uint_as_float(u1 << 16)
                            + __uint_as_float(u2 << 16) + __uint_as_float(u3 << 16);
                        ay += __uint_as_float(u0 & 0xFFFF0000u) + __uint_as_float(u1 & 0xFFFF0000u)
                            + __uint_as_float(u2 & 0xFFFF0000u) + __uint_as_float(u3 & 0xFFFF0000u);
                    }
                    for (; j < end; ++j) {
                        unsigned u = xh32[wcsr[j] * 32 + l];
                        ax += __uint_as_float(u << 16);
                        ay += __uint_as_float(u & 0xFFFF0000u);
                    }
                } else {
                    // overflow fallback: direct global csr (rare; preserves order)
                    for (int g = rowptr[nd]; g < rowend[nd]; ++g) {
                        unsigned u = xh32[csr[g] * 32 + l];
                        ax += __uint_as_float(u << 16);
                        ay += __uint_as_float(u & 0xFFFF0000u);
                    }
                }
            }
            agg_lds[nloc * AGH + l] = bf16_rne(ax * dn) | (bf16_rne(ay * dn) << 16);
        }
    };

    if ((blockIdx.x & 1) == 0) {
#pragma unroll
        for (int c = 0; c < 4; ++c) do_chunk(c);
        do_gather();
#pragma unroll
        for (int c = 4; c < 8; ++c) do_chunk(c);
    } else {
        do_gather();
#pragma unroll
        for (int c = 0; c < 8; ++c) do_chunk(c);
    }

#pragma unroll
    for (int t = 0; t < 4; ++t) {
#pragma unroll
        for (int r = 0; r < 4; ++r) {
            int nd = nbase + (wid << 4) + (lane >> 4) * 4 + r;
            if (nd < N_NODES) out[nd * 64 + t * 16 + (lane & 15)] = acc[t][r];
        }
    }
}

// unfused MFMA KAN (fallback when no xh): reads agg from global; keeps barriers
__global__ __launch_bounds__(NTHR, 8)
void kan_mfma_kernel(const float* __restrict__ x, const float* __restrict__ agg,
                     const unsigned short* __restrict__ Wf, float* __restrict__ out) {
    __shared__ __align__(16) unsigned short A_lds[NB * AST];

    int tid = threadIdx.x;
    int nbase = blockIdx.x * NB;
    int wid = tid >> 6;
    int lane = tid & 63;
    int n = tid & (NB - 1);
    int grp = wid;
    int node = nbase + n;
    bool ok = node < N_NODES;
    const float4 z4 = make_float4(0.f, 0.f, 0.f, 0.f);
    float4 vx[4], va[4];
#pragma unroll
    for (int qq = 0; qq < 4; ++qq)
        vx[qq] = ok ? *(const float4*)&x[node * 64 + qq * CH_IF + grp * 4] : z4;
#pragma unroll
    for (int qq = 0; qq < 4; ++qq)
        va[qq] = ok ? *(const float4*)&agg[node * 64 + qq * CH_IF + grp * 4] : z4;

    f32x4 acc[4];
#pragma unroll
    for (int t = 0; t < 4; ++t) acc[t] = (f32x4){0.f, 0.f, 0.f, 0.f};

    int arow = (wid << 4) + (lane & 15);
    int kfrag = (lane >> 4) * 8;
    const unsigned short* Abase = &A_lds[arow * AST + kfrag];
    const bf16x8* Bbase = (const bf16x8*)Wf + lane;

#pragma unroll
    for (int chunk = 0; chunk < 8; ++chunk) {
        const float4 v4 = (chunk < 4) ? vx[chunk] : va[chunk - 4];
        {
            float vv[4] = {v4.x, v4.y, v4.z, v4.w};
            unsigned short* Arow = &A_lds[n * AST];
#pragma unroll
            for (int jj = 0; jj < 4; ++jj) write_feat(Arow, grp * 4 + jj, vv[jj]);
        }
        __syncthreads();
        {
#pragma unroll
            for (int s = 0; s < 5; ++s) {
                bf16x4 alo = *(const bf16x4*)(Abase + s * 32);
                bf16x4 ahi = *(const bf16x4*)(Abase + s * 32 + 4);
                bf16x8 a = __builtin_shufflevector(alo, ahi, 0, 1, 2, 3, 4, 5, 6, 7);
#pragma unroll
                for (int t = 0; t < 4; ++t) {
                    bf16x8 b = Bbase[((chunk * 5 + s) * 4 + t) * 64];
                    acc[t] = __builtin_amdgcn_mfma_f32_16x16x32_bf16(a, b, acc[t], 0, 0, 0);
                }
            }
        }
        __syncthreads();
    }

#pragma unroll
    for (int t = 0; t < 4; ++t) {
#pragma unroll
        for (int r = 0; r < 4; ++r) {
            int nd = nbase + (wid << 4) + (lane >> 4) * 4 + r;
            if (nd < N_NODES) out[nd * 64 + t * 16 + (lane & 15)] = acc[t][r];
        }
    }
}

extern "C" void kernel_launch(void* const* d_in, const int* in_sizes, int n_in,
                              void* d_out, int out_size, void* d_ws, size_t ws_size,
                              hipStream_t stream) {
    const float* x   = (const float*)d_in[0];
    const float* bwl = (const float*)d_in[1];
    const float* swl = (const float*)d_in[2];
    const float* bwc = (const float*)d_in[3];
    const float* swc = (const float*)d_in[4];
    const int*   ei  = (const int*)d_in[5];
    float* out = (float*)d_out;

    float* ws = (float*)d_ws;
    float* dinv = ws + OFF_DINV;
    int* rowptr = (int*)(ws + OFF_ROWPTR);
    int* rowend = (int*)(ws + OFF_ROWEND);
    unsigned short* Wf = (unsigned short*)(ws + OFF_WT);
    int* bf = (int*)(ws + OFF_BF);
    int* csr = (int*)(ws + OFF_CSR);
    unsigned short* xh = (unsigned short*)(ws + OFF_XH);

    const bool has_csr = ws_size >= (size_t)FIXED_SLOTS * sizeof(float);
    const bool has_xh  = ws_size >= (size_t)FIXED2 * sizeof(float);
    const size_t big_base = has_xh ? (size_t)FIXED2 : (size_t)FIXED_SLOTS;
    const bool big_in_ws = ws_size >= (big_base + (size_t)AGG_ELEMS) * sizeof(float);
    float* bigbuf = (has_csr && big_in_ws) ? (ws + big_base) : out;
    int2* pairs = (int2*)bigbuf;   // dead before any out write (consumed by bucket_build)
    float* agg = bigbuf;           // used only by unfused fallback paths

    if (has_csr) {
        wprep_kernel<<<(WF_U16 + 255) / 256, 256, 0, stream>>>(bwl, swl, bwc, swc, Wf, bf);
        bucket_bin_kernel<<<(N_EDGES + EPB - 1) / EPB, 256, 0, stream>>>(ei, bf, pairs);
        bucket_build_kernel<<<NBUCK_USED, BUCK_N, 0, stream>>>(pairs, bf, rowptr, rowend, dinv, csr);
        if (has_xh) {
            xprep2_kernel<<<(N_NODES * IN_F / 4 + 255) / 256, 256, 0, stream>>>(x, dinv, xh);
            kan_fused_kernel<<<(N_NODES + NB - 1) / NB, NTHR, 0, stream>>>(
                x, xh, csr, rowptr, rowend, dinv, Wf, out);
        } else {
            gather_kernel<<<(N_NODES * 64 + 255) / 256, 256, 0, stream>>>(x, csr, rowptr, rowend, dinv, agg);
            kan_mfma_kernel<<<(N_NODES + NB - 1) / NB, NTHR, 0, stream>>>(x, agg, Wf, out);
        }
    } else {
        float* deg = dinv;
        hipMemsetAsync(deg, 0, (size_t)NODES_PAD * sizeof(float), stream);
        deg_kernel<<<(N_EDGES + 255) / 256, 256, 0, stream>>>(ei, deg);
        dinv_kernel<<<(N_NODES + 255) / 256, 256, 0, stream>>>(deg);
        hipMemsetAsync(agg, 0, (size_t)AGG_ELEMS * sizeof(float), stream);
        long long scatter_threads = (long long)N_EDGES * 64;
        int scatter_blocks = (int)((scatter_threads + 255) / 256);
        scatter_kernel<<<scatter_blocks, 256, 0, stream>>>(x, ei, deg, agg);
        wprep_kernel<<<(WF_U16 + 255) / 256, 256, 0, stream>>>(bwl, swl, bwc, swc, Wf, (int*)0);
        kan_mfma_kernel<<<(N_NODES + NB - 1) / NB, NTHR, 0, stream>>>(x, agg, Wf, out);
    }
}

// Round 25
// 140.660 us; speedup vs baseline: 1.2896x; 1.0660x over previous
//
#include <hip/hip_runtime.h>
#include <math.h>

#define N_NODES 100000
#define N_EDGES 1600000
#define IN_F 64
#define OUT_F 64

// KAN GEMM K layout: k = (path*64 + i)*10 + c; c=0..7 spline bases, c=8 silu,
// c=9 zero pad. K'=1280. Chunk = 16 in-feats = 160 k = 5 MFMA K-steps of 32.
#define K_SLOT 10
#define CH_IF 16
#define AST 172            // A_lds row stride in bf16; bank period 16
#define AGH 33             // agg_lds row stride in u32 (bf16x2); 33%32==1
#define NB 64              // nodes per block (kan)
#define NTHR 256
#define EMAXW 448          // per-wave csr slice capacity (mean 256, +12 sigma)

// bucketed CSR build (fixed capacity)
#define NBUCK 256
#define NBUCK_USED 196
#define BSH 9
#define BCAP 9728          // mean 8192 + 17 sigma
#define BUCK_N 512
#define EPT 8
#define EPB 2048

// ws layout (f32 slots)
#define NODES_PAD 100352
#define WF_U16 (8 * 20 * 512)
#define WG_SLOTS (WF_U16 / 2)
#define CSR_CAP (NBUCK_USED * BCAP)
#define OFF_DINV 0
#define OFF_ROWPTR (OFF_DINV + NODES_PAD)
#define OFF_ROWEND (OFF_ROWPTR + NODES_PAD)
#define OFF_WT (OFF_ROWEND + NODES_PAD)
#define OFF_BF (OFF_WT + WG_SLOTS)
#define OFF_CSR (OFF_BF + 256)
#define FIXED_SLOTS (OFF_CSR + CSR_CAP)
#define XH_SLOTS (N_NODES * IN_F / 2)
#define OFF_XH FIXED_SLOTS
#define FIXED2 (FIXED_SLOTS + XH_SLOTS)
#define AGG_ELEMS (N_NODES * IN_F)

typedef __attribute__((ext_vector_type(8))) short bf16x8;
typedef __attribute__((ext_vector_type(4))) short bf16x4;
typedef __attribute__((ext_vector_type(4))) float f32x4;

__device__ __forceinline__ unsigned int bf16_rne(float v) {
    unsigned int u = __float_as_uint(v);
    u += 0x7FFFu + ((u >> 16) & 1u);
    return u >> 16;
}

// ---- bin edges: LDS counting-sort by bucket -> coalesced pairs write-out ----
__global__ __launch_bounds__(256)
void bucket_bin_kernel(const int* __restrict__ ei, int* __restrict__ bf,
                       int2* __restrict__ pairs) {
    __shared__ int lh[NBUCK];      // per-bucket count
    __shared__ int lbs[NBUCK];     // scan -> local exclusive base
    __shared__ int lgb[NBUCK];     // global base per bucket
    __shared__ int2 spair[EPB];    // staged pairs (sorted by bucket)
    __shared__ int  sdst[EPB];     // global dest per staged slot
    int t = threadIdx.x;
    lh[t] = 0;
    __syncthreads();
    int e0 = blockIdx.x * EPB;
    int nE = N_EDGES - e0; if (nE > EPB) nE = EPB; if (nE < 0) nE = 0;
    int d[EPT], s[EPT], lp[EPT];
#pragma unroll
    for (int k = 0; k < EPT; ++k) {
        int idx = k * 256 + t;
        bool ok = idx < nE;
        int e = e0 + idx;
        d[k] = ok ? ei[N_EDGES + e] : -1;
        s[k] = ok ? ei[e] : 0;
        lp[k] = ok ? atomicAdd(&lh[d[k] >> BSH], 1) : 0;
    }
    __syncthreads();
    int v = lh[t];
    lbs[t] = v;
    __syncthreads();
    for (int off = 1; off < NBUCK; off <<= 1) {
        int add = (t >= off) ? lbs[t - off] : 0;
        __syncthreads();
        lbs[t] += add;
        __syncthreads();
    }
    int excl = lbs[t] - v;
    if (v) {
        int r = atomicAdd(&bf[t], v);
        int cap = (t + 1) * BCAP - v;
        lgb[t] = r > cap ? cap : r;   // defensive clamp (never triggers at 17 sigma)
    }
    __syncthreads();
    lbs[t] = excl;
    __syncthreads();
#pragma unroll
    for (int k = 0; k < EPT; ++k) {
        if (d[k] >= 0) {
            int b = d[k] >> BSH;
            int sp = lbs[b] + lp[k];
            spair[sp] = make_int2(d[k], s[k]);
            sdst[sp] = lgb[b] + lp[k];
        }
    }
    __syncthreads();
    for (int p = t; p < nE; p += 256) pairs[sdst[p]] = spair[p];
}

// one block per bucket: local deg hist, scan -> rowptr/rowend/dinv, csr fill
__global__ __launch_bounds__(BUCK_N)
void bucket_build_kernel(const int2* __restrict__ pairs, const int* __restrict__ bf,
                         int* __restrict__ rowptr, int* __restrict__ rowend,
                         float* __restrict__ dinv, int* __restrict__ csr) {
    __shared__ int ldeg[BUCK_N];
    __shared__ int sb[BUCK_N];
    __shared__ int lpos[BUCK_N];
    int t = threadIdx.x;
    int b = blockIdx.x;
    int base = b * BCAP;
    int cnt = bf[b] - base;
    if (cnt > BCAP) cnt = BCAP;
    ldeg[t] = 0;
    __syncthreads();
    for (int j = t; j < cnt; j += BUCK_N) atomicAdd(&ldeg[pairs[base + j].x & (BUCK_N - 1)], 1);
    __syncthreads();
    int v = ldeg[t];
    sb[t] = v;
    __syncthreads();
    for (int off = 1; off < BUCK_N; off <<= 1) {
        int add = (t >= off) ? sb[t - off] : 0;
        __syncthreads();
        sb[t] += add;
        __syncthreads();
    }
    int excl = sb[t] - v;
    int node = (b << BSH) + t;
    if (node < N_NODES) {
        rowptr[node] = base + excl;
        rowend[node] = base + excl + v;
        dinv[node] = (v > 0) ? rsqrtf((float)v) : 0.0f;
    }
    lpos[t] = base + excl;
    __syncthreads();
    for (int j = t; j < cnt; j += BUCK_N) {
        int2 p = pairs[base + j];
        int pos = atomicAdd(&lpos[p.x & (BUCK_N - 1)], 1);
        csr[pos] = p.y;
    }
}

// xprep (after build): xh[n][f] = bf16(x[n][f] * dinv[n])
__global__ __launch_bounds__(256)
void xprep2_kernel(const float* __restrict__ x, const float* __restrict__ dinv,
                   unsigned short* __restrict__ xh) {
    int i = blockIdx.x * 256 + threadIdx.x;
    if (i * 4 >= N_NODES * IN_F) return;
    int node = i >> 4;                     // (i*4)/64
    float dn = dinv[node];
    float4 v = *(const float4*)&x[i * 4];
    uint2 u;
    u.x = bf16_rne(v.x * dn) | (bf16_rne(v.y * dn) << 16);
    u.y = bf16_rne(v.z * dn) | (bf16_rne(v.w * dn) << 16);
    *(uint2*)&xh[i * 4] = u;
}

// gather (f32 x): fallback when ws can't hold xh
__global__ __launch_bounds__(256)
void gather_kernel(const float* __restrict__ x, const int* __restrict__ csr,
                   const int* __restrict__ rowptr, const int* __restrict__ rowend,
                   const float* __restrict__ dinv, float* __restrict__ agg) {
    int wid = (int)((blockIdx.x * 256 + threadIdx.x) >> 6);
    int lane = threadIdx.x & 63;
    if (wid >= N_NODES) return;
    int start = rowptr[wid];
    int end = rowend[wid];
    float acc = 0.0f;
    int j = start;
    for (; j + 3 < end; j += 4) {
        int s0 = csr[j], s1 = csr[j + 1], s2 = csr[j + 2], s3 = csr[j + 3];
        float a0 = x[s0 * 64 + lane] * dinv[s0];
        float a1 = x[s1 * 64 + lane] * dinv[s1];
        float a2 = x[s2 * 64 + lane] * dinv[s2];
        float a3 = x[s3 * 64 + lane] * dinv[s3];
        acc += a0 + a1 + a2 + a3;
    }
    for (; j < end; ++j) {
        int s = csr[j];
        acc += x[s * 64 + lane] * dinv[s];
    }
    agg[wid * 64 + lane] = acc * dinv[wid];
}

// ---- fallback (ws too small): f32 atomic scatter ----
__global__ void deg_kernel(const int* __restrict__ ei, float* __restrict__ deg) {
    int e = blockIdx.x * blockDim.x + threadIdx.x;
    if (e < N_EDGES) atomicAdd(&deg[ei[N_EDGES + e]], 1.0f);
}
__global__ void dinv_kernel(float* __restrict__ deg) {
    int n = blockIdx.x * blockDim.x + threadIdx.x;
    if (n < N_NODES) {
        float d = deg[n];
        deg[n] = (d > 0.0f) ? rsqrtf(d) : 0.0f;
    }
}
__global__ void scatter_kernel(const float* __restrict__ x, const int* __restrict__ ei,
                               const float* __restrict__ dinv, float* __restrict__ agg) {
    long long gtid = (long long)blockIdx.x * blockDim.x + threadIdx.x;
    int wid = (int)(gtid >> 6);
    int lane = threadIdx.x & 63;
    if (wid >= N_EDGES) return;
    int s = ei[wid];
    int d = ei[N_EDGES + wid];
    float c = dinv[s] * dinv[d];
    atomicAdd(&agg[d * 64 + lane], x[s * 64 + lane] * c);
}

// Wf in MFMA fragment order + bf cursor init (bf may be null in fallback path)
__global__ void wprep_kernel(const float* __restrict__ bwl, const float* __restrict__ swl,
                             const float* __restrict__ bwc, const float* __restrict__ swc,
                             unsigned short* __restrict__ Wf, int* __restrict__ bf) {
    int gid = blockIdx.x * blockDim.x + threadIdx.x;
    if (bf && gid < NBUCK) bf[gid] = gid * BCAP;
    if (gid >= WF_U16) return;
    int fr = gid >> 9;
    int lj = gid & 511;
    int lane = lj >> 3, j = lj & 7;
    int ch = fr / 20, r2 = fr - ch * 20;
    int s = r2 >> 2, t = r2 & 3;
    int o = t * 16 + (lane & 15);
    int kk = ((lane >> 4) << 3) + s * 32 + j;
    int iL = kk / K_SLOT, c = kk - iL * K_SLOT;
    int i = (ch & 3) * CH_IF + iL;
    int path = ch >> 2;
    const float* bw = path ? bwc : bwl;
    const float* sw = path ? swc : swl;
    float v = 0.0f;
    if (c == 8) v = bw[o * IN_F + i];
    else if (c < 8) v = sw[o * 512 + i * 8 + c];
    Wf[gid] = (unsigned short)bf16_rne(v);
}

// shared feature-write helper
__device__ __forceinline__ void write_feat(unsigned short* Arow, int iL, float v) {
    unsigned int* Au = (unsigned int*)(Arow + iL * K_SLOT);
    float sig = __builtin_amdgcn_rcpf(1.0f + __expf(-v));
    Au[0] = 0u; Au[1] = 0u; Au[2] = 0u; Au[3] = 0u;
    Au[4] = bf16_rne(v * sig);
    float s5 = (v + 2.2f) * 2.5f;
    float fm = floorf(s5);
    int m = (int)fm;
    if (m >= 0 && m <= 10) {
        float t = s5 - fm;
        float omt = 1.0f - t;
        float t2 = t * t, t3 = t2 * t;
        float n0 = omt * omt * omt * (1.0f / 6.0f);
        float n3 = t3 * (1.0f / 6.0f);
        float n1 = 0.66666666f - t2 + 0.5f * t3;
        float n2 = 1.0f - n0 - n1 - n3;
        unsigned short* As = Arow + iL * K_SLOT;
        if (m >= 3)           As[m - 3] = (unsigned short)bf16_rne(n0);
        if (m >= 2 && m <= 9) As[m - 2] = (unsigned short)bf16_rne(n1);
        if (m >= 1 && m <= 8) As[m - 1] = (unsigned short)bf16_rne(n2);
        if (m <= 7)           As[m]     = (unsigned short)bf16_rne(n3);
    }
}

// FUSED gather + MFMA KAN: barrier-free, wave-self-contained, csr-LDS-staged,
// parity-staggered. Gather v2: 16 lanes/node x 4 nodes (uint2 = 4 feats/lane)
// -> 2x rows in flight per wave, same line count per edge, bit-identical sums.
__global__ __launch_bounds__(NTHR, 4)
void kan_fused_kernel(const float* __restrict__ x, const unsigned short* __restrict__ xh,
                      const int* __restrict__ csr, const int* __restrict__ rowptr,
                      const int* __restrict__ rowend, const float* __restrict__ dinv,
                      const unsigned short* __restrict__ Wf, float* __restrict__ out) {
    __shared__ __align__(16) unsigned short A_lds[NB * AST];   // 22016 B
    __shared__ unsigned int agg_lds[NB * AGH];                 // 8448 B
    __shared__ int csr_lds[4 * EMAXW];                         // 7168 B

    int tid = threadIdx.x;
    int nbase = blockIdx.x * NB;
    int wid = tid >> 6;
    int lane = tid & 63;
    int nloc0 = (wid << 4) + (lane & 15);
    int q = lane >> 4;
    int node0 = nbase + nloc0;
    bool ok0 = node0 < N_NODES;

    const float4 z4 = make_float4(0.f, 0.f, 0.f, 0.f);
    float4 vx[4];
#pragma unroll
    for (int c = 0; c < 4; ++c)
        vx[c] = ok0 ? *(const float4*)&x[node0 * 64 + c * CH_IF + q * 4] : z4;

    // ---- stage wave's contiguous csr slice into LDS (wave-local, no barrier)
    int wn0 = nbase + (wid << 4);
    int s0w = 0, slenw = 0;
    int* wcsr = &csr_lds[wid * EMAXW];
    if (wn0 < N_NODES) {
        int wnL = wn0 + 15;
        if (wnL >= N_NODES) wnL = N_NODES - 1;
        s0w = rowptr[wn0];
        slenw = rowend[wnL] - s0w;
        int cap = slenw < EMAXW ? slenw : EMAXW;
        for (int i = lane; i < cap; i += 64) wcsr[i] = csr[s0w + i];
    }

    f32x4 acc[4];
#pragma unroll
    for (int t = 0; t < 4; ++t) acc[t] = (f32x4){0.f, 0.f, 0.f, 0.f};

    int kfrag = (lane >> 4) * 8;
    const unsigned short* Abase = &A_lds[nloc0 * AST + kfrag];
    unsigned short* Arow = &A_lds[nloc0 * AST];
    const bf16x8* Bbase = (const bf16x8*)Wf + lane;

    auto do_chunk = [&](int chunk) {
        float vv[4];
        if (chunk < 4) {
            vv[0] = vx[chunk].x; vv[1] = vx[chunk].y; vv[2] = vx[chunk].z; vv[3] = vx[chunk].w;
        } else {
            int b2 = (chunk - 4) * 8 + q * 2;
            unsigned u0 = agg_lds[nloc0 * AGH + b2];
            unsigned u1 = agg_lds[nloc0 * AGH + b2 + 1];
            vv[0] = __uint_as_float(u0 << 16);
            vv[1] = __uint_as_float(u0 & 0xFFFF0000u);
            vv[2] = __uint_as_float(u1 << 16);
            vv[3] = __uint_as_float(u1 & 0xFFFF0000u);
        }
#pragma unroll
        for (int jj = 0; jj < 4; ++jj) write_feat(Arow, q * 4 + jj, vv[jj]);
#pragma unroll
        for (int s = 0; s < 5; ++s) {
            bf16x4 alo = *(const bf16x4*)(Abase + s * 32);
            bf16x4 ahi = *(const bf16x4*)(Abase + s * 32 + 4);
            bf16x8 a = __builtin_shufflevector(alo, ahi, 0, 1, 2, 3, 4, 5, 6, 7);
#pragma unroll
            for (int t = 0; t < 4; ++t) {
                bf16x8 b = Bbase[((chunk * 5 + s) * 4 + t) * 64];
                acc[t] = __builtin_amdgcn_mfma_f32_16x16x32_bf16(a, b, acc[t], 0, 0, 0);
            }
        }
    };

    auto do_gather = [&]() {
        int grp4 = lane >> 4;          // 0..3: node within quad
        int l4 = lane & 15;            // feature quad: features 4*l4 .. 4*l4+3
        const uint2* xh64 = (const uint2*)xh;   // row = 16 uint2
        for (int p = 0; p < 4; ++p) {
            int nloc = (wid << 4) + (p << 2) + grp4;
            int nd = nbase + nloc;
            float a0 = 0.f, a1 = 0.f, a2 = 0.f, a3 = 0.f, dn = 0.f;
            if (nd < N_NODES) {
                dn = dinv[nd];
                int j = rowptr[nd] - s0w;
                int end = rowend[nd] - s0w;
                if (end <= EMAXW) {
                    for (; j + 15 < end; j += 16) {
                        int sa[16]; uint2 ua[16];
#pragma unroll
                        for (int k = 0; k < 16; ++k) sa[k] = wcsr[j + k];
#pragma unroll
                        for (int k = 0; k < 16; ++k) ua[k] = xh64[sa[k] * 16 + l4];
#pragma unroll
                        for (int k = 0; k < 16; ++k) {
                            a0 += __uint_as_float(ua[k].x << 16);
                            a1 += __uint_as_float(ua[k].x & 0xFFFF0000u);
                            a2 += __uint_as_float(ua[k].y << 16);
                            a3 += __uint_as_float(ua[k].y & 0xFFFF0000u);
                        }
                    }
                    for (; j + 3 < end; j += 4) {
                        int s0 = wcsr[j], s1 = wcsr[j + 1], s2 = wcsr[j + 2], s3 = wcsr[j + 3];
                        uint2 u0 = xh64[s0 * 16 + l4], u1 = xh64[s1 * 16 + l4];
                        uint2 u2 = xh64[s2 * 16 + l4], u3 = xh64[s3 * 16 + l4];
                        a0 += __uint_as_float(u0.x << 16) + __uint_as_float(u1.x << 16)
                            + __uint_as_float(u2.x << 16) + __uint_as_float(u3.x << 16);
                        a1 += __uint_as_float(u0.x & 0xFFFF0000u) + __uint_as_float(u1.x & 0xFFFF0000u)
                            + __uint_as_float(u2.x & 0xFFFF0000u) + __uint_as_float(u3.x & 0xFFFF0000u);
                        a2 += __uint_as_float(u0.y << 16) + __uint_as_float(u1.y << 16)
                            + __uint_as_float(u2.y << 16) + __uint_as_float(u3.y << 16);
                        a3 += __uint_as_float(u0.y & 0xFFFF0000u) + __uint_as_float(u1.y & 0xFFFF0000u)
                            + __uint_as_float(u2.y & 0xFFFF0000u) + __uint_as_float(u3.y & 0xFFFF0000u);
                    }
                    for (; j < end; ++j) {
                        uint2 u = xh64[wcsr[j] * 16 + l4];
                        a0 += __uint_as_float(u.x << 16);
                        a1 += __uint_as_float(u.x & 0xFFFF0000u);
                        a2 += __uint_as_float(u.y << 16);
                        a3 += __uint_as_float(u.y & 0xFFFF0000u);
                    }
                } else {
                    // overflow fallback: direct global csr (rare; preserves order)
                    for (int g = rowptr[nd]; g < rowend[nd]; ++g) {
                        uint2 u = xh64[csr[g] * 16 + l4];
                        a0 += __uint_as_float(u.x << 16);
                        a1 += __uint_as_float(u.x & 0xFFFF0000u);
                        a2 += __uint_as_float(u.y << 16);
                        a3 += __uint_as_float(u.y & 0xFFFF0000u);
                    }
                }
            }
            agg_lds[nloc * AGH + 2 * l4]     = bf16_rne(a0 * dn) | (bf16_rne(a1 * dn) << 16);
            agg_lds[nloc * AGH + 2 * l4 + 1] = bf16_rne(a2 * dn) | (bf16_rne(a3 * dn) << 16);
        }
    };

    if ((blockIdx.x & 1) == 0) {
#pragma unroll
        for (int c = 0; c < 4; ++c) do_chunk(c);
        do_gather();
#pragma unroll
        for (int c = 4; c < 8; ++c) do_chunk(c);
    } else {
        do_gather();
#pragma unroll
        for (int c = 0; c < 8; ++c) do_chunk(c);
    }

#pragma unroll
    for (int t = 0; t < 4; ++t) {
#pragma unroll
        for (int r = 0; r < 4; ++r) {
            int nd = nbase + (wid << 4) + (lane >> 4) * 4 + r;
            if (nd < N_NODES) out[nd * 64 + t * 16 + (lane & 15)] = acc[t][r];
        }
    }
}

// unfused MFMA KAN (fallback when no xh): reads agg from global; keeps barriers
__global__ __launch_bounds__(NTHR, 8)
void kan_mfma_kernel(const float* __restrict__ x, const float* __restrict__ agg,
                     const unsigned short* __restrict__ Wf, float* __restrict__ out) {
    __shared__ __align__(16) unsigned short A_lds[NB * AST];

    int tid = threadIdx.x;
    int nbase = blockIdx.x * NB;
    int wid = tid >> 6;
    int lane = tid & 63;
    int n = tid & (NB - 1);
    int grp = wid;
    int node = nbase + n;
    bool ok = node < N_NODES;
    const float4 z4 = make_float4(0.f, 0.f, 0.f, 0.f);
    float4 vx[4], va[4];
#pragma unroll
    for (int qq = 0; qq < 4; ++qq)
        vx[qq] = ok ? *(const float4*)&x[node * 64 + qq * CH_IF + grp * 4] : z4;
#pragma unroll
    for (int qq = 0; qq < 4; ++qq)
        va[qq] = ok ? *(const float4*)&agg[node * 64 + qq * CH_IF + grp * 4] : z4;

    f32x4 acc[4];
#pragma unroll
    for (int t = 0; t < 4; ++t) acc[t] = (f32x4){0.f, 0.f, 0.f, 0.f};

    int arow = (wid << 4) + (lane & 15);
    int kfrag = (lane >> 4) * 8;
    const unsigned short* Abase = &A_lds[arow * AST + kfrag];
    const bf16x8* Bbase = (const bf16x8*)Wf + lane;

#pragma unroll
    for (int chunk = 0; chunk < 8; ++chunk) {
        const float4 v4 = (chunk < 4) ? vx[chunk] : va[chunk - 4];
        {
            float vv[4] = {v4.x, v4.y, v4.z, v4.w};
            unsigned short* Arow = &A_lds[n * AST];
#pragma unroll
            for (int jj = 0; jj < 4; ++jj) write_feat(Arow, grp * 4 + jj, vv[jj]);
        }
        __syncthreads();
        {
#pragma unroll
            for (int s = 0; s < 5; ++s) {
                bf16x4 alo = *(const bf16x4*)(Abase + s * 32);
                bf16x4 ahi = *(const bf16x4*)(Abase + s * 32 + 4);
                bf16x8 a = __builtin_shufflevector(alo, ahi, 0, 1, 2, 3, 4, 5, 6, 7);
#pragma unroll
                for (int t = 0; t < 4; ++t) {
                    bf16x8 b = Bbase[((chunk * 5 + s) * 4 + t) * 64];
                    acc[t] = __builtin_amdgcn_mfma_f32_16x16x32_bf16(a, b, acc[t], 0, 0, 0);
                }
            }
        }
        __syncthreads();
    }

#pragma unroll
    for (int t = 0; t < 4; ++t) {
#pragma unroll
        for (int r = 0; r < 4; ++r) {
            int nd = nbase + (wid << 4) + (lane >> 4) * 4 + r;
            if (nd < N_NODES) out[nd * 64 + t * 16 + (lane & 15)] = acc[t][r];
        }
    }
}

extern "C" void kernel_launch(void* const* d_in, const int* in_sizes, int n_in,
                              void* d_out, int out_size, void* d_ws, size_t ws_size,
                              hipStream_t stream) {
    const float* x   = (const float*)d_in[0];
    const float* bwl = (const float*)d_in[1];
    const float* swl = (const float*)d_in[2];
    const float* bwc = (const float*)d_in[3];
    const float* swc = (const float*)d_in[4];
    const int*   ei  = (const int*)d_in[5];
    float* out = (float*)d_out;

    float* ws = (float*)d_ws;
    float* dinv = ws + OFF_DINV;
    int* rowptr = (int*)(ws + OFF_ROWPTR);
    int* rowend = (int*)(ws + OFF_ROWEND);
    unsigned short* Wf = (unsigned short*)(ws + OFF_WT);
    int* bf = (int*)(ws + OFF_BF);
    int* csr = (int*)(ws + OFF_CSR);
    unsigned short* xh = (unsigned short*)(ws + OFF_XH);

    const bool has_csr = ws_size >= (size_t)FIXED_SLOTS * sizeof(float);
    const bool has_xh  = ws_size >= (size_t)FIXED2 * sizeof(float);
    const size_t big_base = has_xh ? (size_t)FIXED2 : (size_t)FIXED_SLOTS;
    const bool big_in_ws = ws_size >= (big_base + (size_t)AGG_ELEMS) * sizeof(float);
    float* bigbuf = (has_csr && big_in_ws) ? (ws + big_base) : out;
    int2* pairs = (int2*)bigbuf;   // dead before any out write (consumed by bucket_build)
    float* agg = bigbuf;           // used only by unfused fallback paths

    if (has_csr) {
        wprep_kernel<<<(WF_U16 + 255) / 256, 256, 0, stream>>>(bwl, swl, bwc, swc, Wf, bf);
        bucket_bin_kernel<<<(N_EDGES + EPB - 1) / EPB, 256, 0, stream>>>(ei, bf, pairs);
        bucket_build_kernel<<<NBUCK_USED, BUCK_N, 0, stream>>>(pairs, bf, rowptr, rowend, dinv, csr);
        if (has_xh) {
            xprep2_kernel<<<(N_NODES * IN_F / 4 + 255) / 256, 256, 0, stream>>>(x, dinv, xh);
            kan_fused_kernel<<<(N_NODES + NB - 1) / NB, NTHR, 0, stream>>>(
                x, xh, csr, rowptr, rowend, dinv, Wf, out);
        } else {
            gather_kernel<<<(N_NODES * 64 + 255) / 256, 256, 0, stream>>>(x, csr, rowptr, rowend, dinv, agg);
            kan_mfma_kernel<<<(N_NODES + NB - 1) / NB, NTHR, 0, stream>>>(x, agg, Wf, out);
        }
    } else {
        float* deg = dinv;
        hipMemsetAsync(deg, 0, (size_t)NODES_PAD * sizeof(float), stream);
        deg_kernel<<<(N_EDGES + 255) / 256, 256, 0, stream>>>(ei, deg);
        dinv_kernel<<<(N_NODES + 255) / 256, 256, 0, stream>>>(deg);
        hipMemsetAsync(agg, 0, (size_t)AGG_ELEMS * sizeof(float), stream);
        long long scatter_threads = (long long)N_EDGES * 64;
        int scatter_blocks = (int)((scatter_threads + 255) / 256);
        scatter_kernel<<<scatter_blocks, 256, 0, stream>>>(x, ei, deg, agg);
        wprep_kernel<<<(WF_U16 + 255) / 256, 256, 0, stream>>>(bwl, swl, bwc, swc, Wf, (int*)0);
        kan_mfma_kernel<<<(N_NODES + NB - 1) / NB, NTHR, 0, stream>>>(x, agg, Wf, out);
    }
}

// Round 26
// 132.130 us; speedup vs baseline: 1.3728x; 1.0646x over previous
//
#include <hip/hip_runtime.h>
#include <math.h>

#define N_NODES 100000
#define N_EDGES 1600000
#define IN_F 64
#define OUT_F 64

// KAN GEMM K layout: k = (path*64 + i)*10 + c; c=0..7 spline bases, c=8 silu,
// c=9 zero pad. K'=1280. Chunk = 16 in-feats = 160 k = 5 MFMA K-steps of 32.
#define K_SLOT 10
#define CH_IF 16
#define AST 172            // A_lds row stride in bf16; bank period 16
#define AGH 33             // agg_lds row stride in u32 (bf16x2); 33%32==1
#define NB 64              // nodes per block (kan)
#define NTHR 256
#define EMAXW 448          // per-wave csr slice capacity (mean 256, +12 sigma)

// bucketed CSR build (fixed capacity)
#define NBUCK 256
#define NBUCK_USED 196
#define BSH 9
#define BCAP 9728          // mean 8192 + 17 sigma
#define BUCK_N 512
#define EPT 8
#define EPB 2048

// ws layout (f32 slots)
#define NODES_PAD 100352
#define WF_U16 (8 * 20 * 512)
#define WG_SLOTS (WF_U16 / 2)
#define CSR_CAP (NBUCK_USED * BCAP)
#define OFF_DINV 0
#define OFF_ROWPTR (OFF_DINV + NODES_PAD)
#define OFF_ROWEND (OFF_ROWPTR + NODES_PAD)
#define OFF_WT (OFF_ROWEND + NODES_PAD)
#define OFF_BF (OFF_WT + WG_SLOTS)
#define OFF_CSR (OFF_BF + 256)
#define FIXED_SLOTS (OFF_CSR + CSR_CAP)
#define XH_SLOTS (N_NODES * IN_F / 2)
#define OFF_XH FIXED_SLOTS
#define FIXED2 (FIXED_SLOTS + XH_SLOTS)
#define AGG_ELEMS (N_NODES * IN_F)

typedef __attribute__((ext_vector_type(8))) short bf16x8;
typedef __attribute__((ext_vector_type(4))) short bf16x4;
typedef __attribute__((ext_vector_type(4))) float f32x4;

__device__ __forceinline__ unsigned int bf16_rne(float v) {
    unsigned int u = __float_as_uint(v);
    u += 0x7FFFu + ((u >> 16) & 1u);
    return u >> 16;
}

// ---- bin edges: LDS counting-sort by bucket -> coalesced pairs write-out ----
__global__ __launch_bounds__(256)
void bucket_bin_kernel(const int* __restrict__ ei, int* __restrict__ bf,
                       int2* __restrict__ pairs) {
    __shared__ int lh[NBUCK];      // per-bucket count
    __shared__ int lbs[NBUCK];     // scan -> local exclusive base
    __shared__ int lgb[NBUCK];     // global base per bucket
    __shared__ int2 spair[EPB];    // staged pairs (sorted by bucket)
    __shared__ int  sdst[EPB];     // global dest per staged slot
    int t = threadIdx.x;
    lh[t] = 0;
    __syncthreads();
    int e0 = blockIdx.x * EPB;
    int nE = N_EDGES - e0; if (nE > EPB) nE = EPB; if (nE < 0) nE = 0;
    int d[EPT], s[EPT], lp[EPT];
#pragma unroll
    for (int k = 0; k < EPT; ++k) {
        int idx = k * 256 + t;
        bool ok = idx < nE;
        int e = e0 + idx;
        d[k] = ok ? ei[N_EDGES + e] : -1;
        s[k] = ok ? ei[e] : 0;
        lp[k] = ok ? atomicAdd(&lh[d[k] >> BSH], 1) : 0;
    }
    __syncthreads();
    int v = lh[t];
    lbs[t] = v;
    __syncthreads();
    for (int off = 1; off < NBUCK; off <<= 1) {
        int add = (t >= off) ? lbs[t - off] : 0;
        __syncthreads();
        lbs[t] += add;
        __syncthreads();
    }
    int excl = lbs[t] - v;
    if (v) {
        int r = atomicAdd(&bf[t], v);
        int cap = (t + 1) * BCAP - v;
        lgb[t] = r > cap ? cap : r;   // defensive clamp (never triggers at 17 sigma)
    }
    __syncthreads();
    lbs[t] = excl;
    __syncthreads();
#pragma unroll
    for (int k = 0; k < EPT; ++k) {
        if (d[k] >= 0) {
            int b = d[k] >> BSH;
            int sp = lbs[b] + lp[k];
            spair[sp] = make_int2(d[k], s[k]);
            sdst[sp] = lgb[b] + lp[k];
        }
    }
    __syncthreads();
    for (int p = t; p < nE; p += 256) pairs[sdst[p]] = spair[p];
}

// one block per bucket: local deg hist, scan -> rowptr/rowend/dinv, csr fill,
// + merged xprep tail: xh[n][f] = bf16(x[n][f] * rsqrt(deg[n])) for its nodes
__global__ __launch_bounds__(BUCK_N)
void bucket_build_kernel(const int2* __restrict__ pairs, const int* __restrict__ bf,
                         int* __restrict__ rowptr, int* __restrict__ rowend,
                         float* __restrict__ dinv, int* __restrict__ csr,
                         const float* __restrict__ x, unsigned short* __restrict__ xh) {
    __shared__ int ldeg[BUCK_N];
    __shared__ int sb[BUCK_N];
    __shared__ int lpos[BUCK_N];
    int t = threadIdx.x;
    int b = blockIdx.x;
    int base = b * BCAP;
    int cnt = bf[b] - base;
    if (cnt > BCAP) cnt = BCAP;
    ldeg[t] = 0;
    __syncthreads();
    for (int j = t; j < cnt; j += BUCK_N) atomicAdd(&ldeg[pairs[base + j].x & (BUCK_N - 1)], 1);
    __syncthreads();
    int v = ldeg[t];
    sb[t] = v;
    __syncthreads();
    for (int off = 1; off < BUCK_N; off <<= 1) {
        int add = (t >= off) ? sb[t - off] : 0;
        __syncthreads();
        sb[t] += add;
        __syncthreads();
    }
    int excl = sb[t] - v;
    int node = (b << BSH) + t;
    if (node < N_NODES) {
        rowptr[node] = base + excl;
        rowend[node] = base + excl + v;
        dinv[node] = (v > 0) ? rsqrtf((float)v) : 0.0f;
    }
    lpos[t] = base + excl;
    __syncthreads();
    for (int j = t; j < cnt; j += BUCK_N) {
        int2 p = pairs[base + j];
        int pos = atomicAdd(&lpos[p.x & (BUCK_N - 1)], 1);
        csr[pos] = p.y;
    }
    // merged xprep (ldeg stable since the hist barrier): 16 float4 per node
    if (xh) {
        int nodebase = b << BSH;
        for (int f = t; f < BUCK_N * 16; f += BUCK_N) {
            int nl = f >> 4;
            int nd = nodebase + nl;
            if (nd < N_NODES) {
                int dg = ldeg[nl];
                float dn = (dg > 0) ? rsqrtf((float)dg) : 0.0f;
                float4 vv = *(const float4*)&x[nd * 64 + (f & 15) * 4];
                uint2 u;
                u.x = bf16_rne(vv.x * dn) | (bf16_rne(vv.y * dn) << 16);
                u.y = bf16_rne(vv.z * dn) | (bf16_rne(vv.w * dn) << 16);
                *(uint2*)&xh[nd * 64 + (f & 15) * 4] = u;
            }
        }
    }
}

// gather (f32 x): fallback when ws can't hold xh
__global__ __launch_bounds__(256)
void gather_kernel(const float* __restrict__ x, const int* __restrict__ csr,
                   const int* __restrict__ rowptr, const int* __restrict__ rowend,
                   const float* __restrict__ dinv, float* __restrict__ agg) {
    int wid = (int)((blockIdx.x * 256 + threadIdx.x) >> 6);
    int lane = threadIdx.x & 63;
    if (wid >= N_NODES) return;
    int start = rowptr[wid];
    int end = rowend[wid];
    float acc = 0.0f;
    int j = start;
    for (; j + 3 < end; j += 4) {
        int s0 = csr[j], s1 = csr[j + 1], s2 = csr[j + 2], s3 = csr[j + 3];
        float a0 = x[s0 * 64 + lane] * dinv[s0];
        float a1 = x[s1 * 64 + lane] * dinv[s1];
        float a2 = x[s2 * 64 + lane] * dinv[s2];
        float a3 = x[s3 * 64 + lane] * dinv[s3];
        acc += a0 + a1 + a2 + a3;
    }
    for (; j < end; ++j) {
        int s = csr[j];
        acc += x[s * 64 + lane] * dinv[s];
    }
    agg[wid * 64 + lane] = acc * dinv[wid];
}

// ---- fallback (ws too small): f32 atomic scatter ----
__global__ void deg_kernel(const int* __restrict__ ei, float* __restrict__ deg) {
    int e = blockIdx.x * blockDim.x + threadIdx.x;
    if (e < N_EDGES) atomicAdd(&deg[ei[N_EDGES + e]], 1.0f);
}
__global__ void dinv_kernel(float* __restrict__ deg) {
    int n = blockIdx.x * blockDim.x + threadIdx.x;
    if (n < N_NODES) {
        float d = deg[n];
        deg[n] = (d > 0.0f) ? rsqrtf(d) : 0.0f;
    }
}
__global__ void scatter_kernel(const float* __restrict__ x, const int* __restrict__ ei,
                               const float* __restrict__ dinv, float* __restrict__ agg) {
    long long gtid = (long long)blockIdx.x * blockDim.x + threadIdx.x;
    int wid = (int)(gtid >> 6);
    int lane = threadIdx.x & 63;
    if (wid >= N_EDGES) return;
    int s = ei[wid];
    int d = ei[N_EDGES + wid];
    float c = dinv[s] * dinv[d];
    atomicAdd(&agg[d * 64 + lane], x[s * 64 + lane] * c);
}

// Wf in MFMA fragment order + bf cursor init (bf may be null in fallback path)
__global__ void wprep_kernel(const float* __restrict__ bwl, const float* __restrict__ swl,
                             const float* __restrict__ bwc, const float* __restrict__ swc,
                             unsigned short* __restrict__ Wf, int* __restrict__ bf) {
    int gid = blockIdx.x * blockDim.x + threadIdx.x;
    if (bf && gid < NBUCK) bf[gid] = gid * BCAP;
    if (gid >= WF_U16) return;
    int fr = gid >> 9;
    int lj = gid & 511;
    int lane = lj >> 3, j = lj & 7;
    int ch = fr / 20, r2 = fr - ch * 20;
    int s = r2 >> 2, t = r2 & 3;
    int o = t * 16 + (lane & 15);
    int kk = ((lane >> 4) << 3) + s * 32 + j;
    int iL = kk / K_SLOT, c = kk - iL * K_SLOT;
    int i = (ch & 3) * CH_IF + iL;
    int path = ch >> 2;
    const float* bw = path ? bwc : bwl;
    const float* sw = path ? swc : swl;
    float v = 0.0f;
    if (c == 8) v = bw[o * IN_F + i];
    else if (c < 8) v = sw[o * 512 + i * 8 + c];
    Wf[gid] = (unsigned short)bf16_rne(v);
}

// shared feature-write helper
__device__ __forceinline__ void write_feat(unsigned short* Arow, int iL, float v) {
    unsigned int* Au = (unsigned int*)(Arow + iL * K_SLOT);
    float sig = __builtin_amdgcn_rcpf(1.0f + __expf(-v));
    Au[0] = 0u; Au[1] = 0u; Au[2] = 0u; Au[3] = 0u;
    Au[4] = bf16_rne(v * sig);
    float s5 = (v + 2.2f) * 2.5f;
    float fm = floorf(s5);
    int m = (int)fm;
    if (m >= 0 && m <= 10) {
        float t = s5 - fm;
        float omt = 1.0f - t;
        float t2 = t * t, t3 = t2 * t;
        float n0 = omt * omt * omt * (1.0f / 6.0f);
        float n3 = t3 * (1.0f / 6.0f);
        float n1 = 0.66666666f - t2 + 0.5f * t3;
        float n2 = 1.0f - n0 - n1 - n3;
        unsigned short* As = Arow + iL * K_SLOT;
        if (m >= 3)           As[m - 3] = (unsigned short)bf16_rne(n0);
        if (m >= 2 && m <= 9) As[m - 2] = (unsigned short)bf16_rne(n1);
        if (m >= 1 && m <= 8) As[m - 1] = (unsigned short)bf16_rne(n2);
        if (m <= 7)           As[m]     = (unsigned short)bf16_rne(n3);
    }
}

// FUSED gather + MFMA KAN: barrier-free, wave-self-contained, csr-LDS-staged,
// parity-staggered. Gather v3: 8 lanes/node x 8 nodes (uint4 = 8 feats/lane)
// -> one wave-load covers 8 rows (1 KB); fewer load instrs, more bytes in
// flight. Per-feature accumulation order unchanged -> bit-identical output.
__global__ __launch_bounds__(NTHR, 4)
void kan_fused_kernel(const float* __restrict__ x, const unsigned short* __restrict__ xh,
                      const int* __restrict__ csr, const int* __restrict__ rowptr,
                      const int* __restrict__ rowend, const float* __restrict__ dinv,
                      const unsigned short* __restrict__ Wf, float* __restrict__ out) {
    __shared__ __align__(16) unsigned short A_lds[NB * AST];   // 22016 B
    __shared__ unsigned int agg_lds[NB * AGH];                 // 8448 B
    __shared__ int csr_lds[4 * EMAXW];                         // 7168 B

    int tid = threadIdx.x;
    int nbase = blockIdx.x * NB;
    int wid = tid >> 6;
    int lane = tid & 63;
    int nloc0 = (wid << 4) + (lane & 15);
    int q = lane >> 4;
    int node0 = nbase + nloc0;
    bool ok0 = node0 < N_NODES;

    const float4 z4 = make_float4(0.f, 0.f, 0.f, 0.f);
    float4 vx[4];
#pragma unroll
    for (int c = 0; c < 4; ++c)
        vx[c] = ok0 ? *(const float4*)&x[node0 * 64 + c * CH_IF + q * 4] : z4;

    // ---- stage wave's contiguous csr slice into LDS (wave-local, no barrier)
    int wn0 = nbase + (wid << 4);
    int s0w = 0, slenw = 0;
    int* wcsr = &csr_lds[wid * EMAXW];
    if (wn0 < N_NODES) {
        int wnL = wn0 + 15;
        if (wnL >= N_NODES) wnL = N_NODES - 1;
        s0w = rowptr[wn0];
        slenw = rowend[wnL] - s0w;
        int cap = slenw < EMAXW ? slenw : EMAXW;
        for (int i = lane; i < cap; i += 64) wcsr[i] = csr[s0w + i];
    }

    f32x4 acc[4];
#pragma unroll
    for (int t = 0; t < 4; ++t) acc[t] = (f32x4){0.f, 0.f, 0.f, 0.f};

    int kfrag = (lane >> 4) * 8;
    const unsigned short* Abase = &A_lds[nloc0 * AST + kfrag];
    unsigned short* Arow = &A_lds[nloc0 * AST];
    const bf16x8* Bbase = (const bf16x8*)Wf + lane;

    auto do_chunk = [&](int chunk) {
        float vv[4];
        if (chunk < 4) {
            vv[0] = vx[chunk].x; vv[1] = vx[chunk].y; vv[2] = vx[chunk].z; vv[3] = vx[chunk].w;
        } else {
            int b2 = (chunk - 4) * 8 + q * 2;
            unsigned u0 = agg_lds[nloc0 * AGH + b2];
            unsigned u1 = agg_lds[nloc0 * AGH + b2 + 1];
            vv[0] = __uint_as_float(u0 << 16);
            vv[1] = __uint_as_float(u0 & 0xFFFF0000u);
            vv[2] = __uint_as_float(u1 << 16);
            vv[3] = __uint_as_float(u1 & 0xFFFF0000u);
        }
#pragma unroll
        for (int jj = 0; jj < 4; ++jj) write_feat(Arow, q * 4 + jj, vv[jj]);
#pragma unroll
        for (int s = 0; s < 5; ++s) {
            bf16x4 alo = *(const bf16x4*)(Abase + s * 32);
            bf16x4 ahi = *(const bf16x4*)(Abase + s * 32 + 4);
            bf16x8 a = __builtin_shufflevector(alo, ahi, 0, 1, 2, 3, 4, 5, 6, 7);
#pragma unroll
            for (int t = 0; t < 4; ++t) {
                bf16x8 b = Bbase[((chunk * 5 + s) * 4 + t) * 64];
                acc[t] = __builtin_amdgcn_mfma_f32_16x16x32_bf16(a, b, acc[t], 0, 0, 0);
            }
        }
    };

    auto do_gather = [&]() {
        int grp8 = lane >> 3;          // 0..7: node within octet
        int l8 = lane & 7;             // feature octet: feats 8*l8 .. 8*l8+7
        const uint4* xh128 = (const uint4*)xh;   // row = 8 uint4
        for (int p = 0; p < 2; ++p) {
            int nloc = (wid << 4) + (p << 3) + grp8;
            int nd = nbase + nloc;
            float a0 = 0.f, a1 = 0.f, a2 = 0.f, a3 = 0.f;
            float a4 = 0.f, a5 = 0.f, a6 = 0.f, a7 = 0.f;
            float dn = 0.f;
            if (nd < N_NODES) {
                dn = dinv[nd];
                int j = rowptr[nd] - s0w;
                int end = rowend[nd] - s0w;
                if (end <= EMAXW) {
                    for (; j + 15 < end; j += 16) {
                        int sa[16]; uint4 ua[16];
#pragma unroll
                        for (int k = 0; k < 16; ++k) sa[k] = wcsr[j + k];
#pragma unroll
                        for (int k = 0; k < 16; ++k) ua[k] = xh128[sa[k] * 8 + l8];
#pragma unroll
                        for (int k = 0; k < 16; ++k) {
                            a0 += __uint_as_float(ua[k].x << 16);
                            a1 += __uint_as_float(ua[k].x & 0xFFFF0000u);
                            a2 += __uint_as_float(ua[k].y << 16);
                            a3 += __uint_as_float(ua[k].y & 0xFFFF0000u);
                            a4 += __uint_as_float(ua[k].z << 16);
                            a5 += __uint_as_float(ua[k].z & 0xFFFF0000u);
                            a6 += __uint_as_float(ua[k].w << 16);
                            a7 += __uint_as_float(ua[k].w & 0xFFFF0000u);
                        }
                    }
                    for (; j + 3 < end; j += 4) {
                        int sb0 = wcsr[j], sb1 = wcsr[j + 1], sb2 = wcsr[j + 2], sb3 = wcsr[j + 3];
                        uint4 u0 = xh128[sb0 * 8 + l8], u1 = xh128[sb1 * 8 + l8];
                        uint4 u2 = xh128[sb2 * 8 + l8], u3 = xh128[sb3 * 8 + l8];
                        a0 += __uint_as_float(u0.x << 16) + __uint_as_float(u1.x << 16)
                            + __uint_as_float(u2.x << 16) + __uint_as_float(u3.x << 16);
                        a1 += __uint_as_float(u0.x & 0xFFFF0000u) + __uint_as_float(u1.x & 0xFFFF0000u)
                            + __uint_as_float(u2.x & 0xFFFF0000u) + __uint_as_float(u3.x & 0xFFFF0000u);
                        a2 += __uint_as_float(u0.y << 16) + __uint_as_float(u1.y << 16)
                            + __uint_as_float(u2.y << 16) + __uint_as_float(u3.y << 16);
                        a3 += __uint_as_float(u0.y & 0xFFFF0000u) + __uint_as_float(u1.y & 0xFFFF0000u)
                            + __uint_as_float(u2.y & 0xFFFF0000u) + __uint_as_float(u3.y & 0xFFFF0000u);
                        a4 += __uint_as_float(u0.z << 16) + __uint_as_float(u1.z << 16)
                            + __uint_as_float(u2.z << 16) + __uint_as_float(u3.z << 16);
                        a5 += __uint_as_float(u0.z & 0xFFFF0000u) + __uint_as_float(u1.z & 0xFFFF0000u)
                            + __uint_as_float(u2.z & 0xFFFF0000u) + __uint_as_float(u3.z & 0xFFFF0000u);
                        a6 += __uint_as_float(u0.w << 16) + __uint_as_float(u1.w << 16)
                            + __uint_as_float(u2.w << 16) + __uint_as_float(u3.w << 16);
                        a7 += __uint_as_float(u0.w & 0xFFFF0000u) + __uint_as_float(u1.w & 0xFFFF0000u)
                            + __uint_as_float(u2.w & 0xFFFF0000u) + __uint_as_float(u3.w & 0xFFFF0000u);
                    }
                    for (; j < end; ++j) {
                        uint4 u = xh128[wcsr[j] * 8 + l8];
                        a0 += __uint_as_float(u.x << 16);
                        a1 += __uint_as_float(u.x & 0xFFFF0000u);
                        a2 += __uint_as_float(u.y << 16);
                        a3 += __uint_as_float(u.y & 0xFFFF0000u);
                        a4 += __uint_as_float(u.z << 16);
                        a5 += __uint_as_float(u.z & 0xFFFF0000u);
                        a6 += __uint_as_float(u.w << 16);
                        a7 += __uint_as_float(u.w & 0xFFFF0000u);
                    }
                } else {
                    // overflow fallback: direct global csr (rare; preserves order)
                    for (int g = rowptr[nd]; g < rowend[nd]; ++g) {
                        uint4 u = xh128[csr[g] * 8 + l8];
                        a0 += __uint_as_float(u.x << 16);
                        a1 += __uint_as_float(u.x & 0xFFFF0000u);
                        a2 += __uint_as_float(u.y << 16);
                        a3 += __uint_as_float(u.y & 0xFFFF0000u);
                        a4 += __uint_as_float(u.z << 16);
                        a5 += __uint_as_float(u.z & 0xFFFF0000u);
                        a6 += __uint_as_float(u.w << 16);
                        a7 += __uint_as_float(u.w & 0xFFFF0000u);
                    }
                }
            }
            int base2 = nloc * AGH + 4 * l8;
            agg_lds[base2]     = bf16_rne(a0 * dn) | (bf16_rne(a1 * dn) << 16);
            agg_lds[base2 + 1] = bf16_rne(a2 * dn) | (bf16_rne(a3 * dn) << 16);
            agg_lds[base2 + 2] = bf16_rne(a4 * dn) | (bf16_rne(a5 * dn) << 16);
            agg_lds[base2 + 3] = bf16_rne(a6 * dn) | (bf16_rne(a7 * dn) << 16);
        }
    };

    if ((blockIdx.x & 1) == 0) {
#pragma unroll
        for (int c = 0; c < 4; ++c) do_chunk(c);
        do_gather();
#pragma unroll
        for (int c = 4; c < 8; ++c) do_chunk(c);
    } else {
        do_gather();
#pragma unroll
        for (int c = 0; c < 8; ++c) do_chunk(c);
    }

#pragma unroll
    for (int t = 0; t < 4; ++t) {
#pragma unroll
        for (int r = 0; r < 4; ++r) {
            int nd = nbase + (wid << 4) + (lane >> 4) * 4 + r;
            if (nd < N_NODES) out[nd * 64 + t * 16 + (lane & 15)] = acc[t][r];
        }
    }
}

// unfused MFMA KAN (fallback when no xh): reads agg from global; keeps barriers
__global__ __launch_bounds__(NTHR, 8)
void kan_mfma_kernel(const float* __restrict__ x, const float* __restrict__ agg,
                     const unsigned short* __restrict__ Wf, float* __restrict__ out) {
    __shared__ __align__(16) unsigned short A_lds[NB * AST];

    int tid = threadIdx.x;
    int nbase = blockIdx.x * NB;
    int wid = tid >> 6;
    int lane = tid & 63;
    int n = tid & (NB - 1);
    int grp = wid;
    int node = nbase + n;
    bool ok = node < N_NODES;
    const float4 z4 = make_float4(0.f, 0.f, 0.f, 0.f);
    float4 vx[4], va[4];
#pragma unroll
    for (int qq = 0; qq < 4; ++qq)
        vx[qq] = ok ? *(const float4*)&x[node * 64 + qq * CH_IF + grp * 4] : z4;
#pragma unroll
    for (int qq = 0; qq < 4; ++qq)
        va[qq] = ok ? *(const float4*)&agg[node * 64 + qq * CH_IF + grp * 4] : z4;

    f32x4 acc[4];
#pragma unroll
    for (int t = 0; t < 4; ++t) acc[t] = (f32x4){0.f, 0.f, 0.f, 0.f};

    int arow = (wid << 4) + (lane & 15);
    int kfrag = (lane >> 4) * 8;
    const unsigned short* Abase = &A_lds[arow * AST + kfrag];
    const bf16x8* Bbase = (const bf16x8*)Wf + lane;

#pragma unroll
    for (int chunk = 0; chunk < 8; ++chunk) {
        const float4 v4 = (chunk < 4) ? vx[chunk] : va[chunk - 4];
        {
            float vv[4] = {v4.x, v4.y, v4.z, v4.w};
            unsigned short* Arow = &A_lds[n * AST];
#pragma unroll
            for (int jj = 0; jj < 4; ++jj) write_feat(Arow, grp * 4 + jj, vv[jj]);
        }
        __syncthreads();
        {
#pragma unroll
            for (int s = 0; s < 5; ++s) {
                bf16x4 alo = *(const bf16x4*)(Abase + s * 32);
                bf16x4 ahi = *(const bf16x4*)(Abase + s * 32 + 4);
                bf16x8 a = __builtin_shufflevector(alo, ahi, 0, 1, 2, 3, 4, 5, 6, 7);
#pragma unroll
                for (int t = 0; t < 4; ++t) {
                    bf16x8 b = Bbase[((chunk * 5 + s) * 4 + t) * 64];
                    acc[t] = __builtin_amdgcn_mfma_f32_16x16x32_bf16(a, b, acc[t], 0, 0, 0);
                }
            }
        }
        __syncthreads();
    }

#pragma unroll
    for (int t = 0; t < 4; ++t) {
#pragma unroll
        for (int r = 0; r < 4; ++r) {
            int nd = nbase + (wid << 4) + (lane >> 4) * 4 + r;
            if (nd < N_NODES) out[nd * 64 + t * 16 + (lane & 15)] = acc[t][r];
        }
    }
}

extern "C" void kernel_launch(void* const* d_in, const int* in_sizes, int n_in,
                              void* d_out, int out_size, void* d_ws, size_t ws_size,
                              hipStream_t stream) {
    const float* x   = (const float*)d_in[0];
    const float* bwl = (const float*)d_in[1];
    const float* swl = (const float*)d_in[2];
    const float* bwc = (const float*)d_in[3];
    const float* swc = (const float*)d_in[4];
    const int*   ei  = (const int*)d_in[5];
    float* out = (float*)d_out;

    float* ws = (float*)d_ws;
    float* dinv = ws + OFF_DINV;
    int* rowptr = (int*)(ws + OFF_ROWPTR);
    int* rowend = (int*)(ws + OFF_ROWEND);
    unsigned short* Wf = (unsigned short*)(ws + OFF_WT);
    int* bf = (int*)(ws + OFF_BF);
    int* csr = (int*)(ws + OFF_CSR);
    unsigned short* xh = (unsigned short*)(ws + OFF_XH);

    const bool has_csr = ws_size >= (size_t)FIXED_SLOTS * sizeof(float);
    const bool has_xh  = ws_size >= (size_t)FIXED2 * sizeof(float);
    const size_t big_base = has_xh ? (size_t)FIXED2 : (size_t)FIXED_SLOTS;
    const bool big_in_ws = ws_size >= (big_base + (size_t)AGG_ELEMS) * sizeof(float);
    float* bigbuf = (has_csr && big_in_ws) ? (ws + big_base) : out;
    int2* pairs = (int2*)bigbuf;   // dead before any out write (consumed by bucket_build)
    float* agg = bigbuf;           // used only by unfused fallback paths

    if (has_csr) {
        wprep_kernel<<<(WF_U16 + 255) / 256, 256, 0, stream>>>(bwl, swl, bwc, swc, Wf, bf);
        bucket_bin_kernel<<<(N_EDGES + EPB - 1) / EPB, 256, 0, stream>>>(ei, bf, pairs);
        bucket_build_kernel<<<NBUCK_USED, BUCK_N, 0, stream>>>(
            pairs, bf, rowptr, rowend, dinv, csr, x, has_xh ? xh : (unsigned short*)0);
        if (has_xh) {
            kan_fused_kernel<<<(N_NODES + NB - 1) / NB, NTHR, 0, stream>>>(
                x, xh, csr, rowptr, rowend, dinv, Wf, out);
        } else {
            gather_kernel<<<(N_NODES * 64 + 255) / 256, 256, 0, stream>>>(x, csr, rowptr, rowend, dinv, agg);
            kan_mfma_kernel<<<(N_NODES + NB - 1) / NB, NTHR, 0, stream>>>(x, agg, Wf, out);
        }
    } else {
        float* deg = dinv;
        hipMemsetAsync(deg, 0, (size_t)NODES_PAD * sizeof(float), stream);
        deg_kernel<<<(N_EDGES + 255) / 256, 256, 0, stream>>>(ei, deg);
        dinv_kernel<<<(N_NODES + 255) / 256, 256, 0, stream>>>(deg);
        hipMemsetAsync(agg, 0, (size_t)AGG_ELEMS * sizeof(float), stream);
        long long scatter_threads = (long long)N_EDGES * 64;
        int scatter_blocks = (int)((scatter_threads + 255) / 256);
        scatter_kernel<<<scatter_blocks, 256, 0, stream>>>(x, ei, deg, agg);
        wprep_kernel<<<(WF_U16 + 255) / 256, 256, 0, stream>>>(bwl, swl, bwc, swc, Wf, (int*)0);
        kan_mfma_kernel<<<(N_NODES + NB - 1) / NB, NTHR, 0, stream>>>(x, agg, Wf, out);
    }
}